// Round 1
// baseline (317.195 us; speedup 1.0000x reference)
//
#include <hip/hip_runtime.h>
#include <hip/hip_bf16.h>
#include <cstdint>

// Problem constants
#define NB   2
#define NC   256
#define NN   4096   // H*W = 64*64
#define NH   8      // heads
#define HSZ  32     // head size
#define NF   256    // FEAT
#define N3F  768

typedef __bf16 bf16x8 __attribute__((ext_vector_type(8)));
typedef float  floatx4 __attribute__((ext_vector_type(4)));

// log2(e)/sqrt(32): folded into q so softmax runs in exp2 domain
#define QSCALE 0.25506601622184f

// ---------------- K0: convert weights to bf16 ----------------
__global__ void k_convert_w(const float* __restrict__ wqkv, const float* __restrict__ wproj,
                            __bf16* __restrict__ wqb, __bf16* __restrict__ wpb) {
    int i = blockIdx.x * 256 + threadIdx.x;   // 262144 total
    if (i < 196608) wqb[i] = (__bf16)wqkv[i];
    else            wpb[i - 196608] = (__bf16)wproj[i - 196608];
}

// ---------------- K1: preact silu, store y as [b][n][c] bf16 ----------------
__global__ void k_preact(const float* __restrict__ x, const float* __restrict__ pab,
                         const float* __restrict__ pqb, __bf16* __restrict__ y) {
    int t = blockIdx.x * 256 + threadIdx.x;   // 524288 threads, 4 elems each
    int base = t * 4;                          // linear over [b][c][n]
    int c = (base >> 12) & 255;
    int b = base >> 20;
    int n = base & 4095;
    const float4 xv = *(const float4*)(x + base);
    float bias = pab[c], qb = pqb[c];
    float vs[4] = {xv.x, xv.y, xv.z, xv.w};
    __bf16* yb = y + ((size_t)b * NN) * NC + c;
#pragma unroll
    for (int i = 0; i < 4; i++) {
        float s = vs[i] + bias;
        float r = s / (1.f + __expf(-s)) + qb;   // silu + pre_qkv_bias
        yb[(size_t)(n + i) * NC] = (__bf16)r;    // scattered bf16 write, L2-absorbed
    }
}

// ---------------- K2: QKV GEMM out[n,o] = y_nc * w_qkv^T + epilogue ----------------
__launch_bounds__(256)
__global__ void k_qkv(const __bf16* __restrict__ y, const __bf16* __restrict__ wb,
                      const float* __restrict__ bqkv,
                      const float* __restrict__ peqh, const float* __restrict__ peqw,
                      const float* __restrict__ pekh, const float* __restrict__ pekw,
                      const float* __restrict__ mm, const float* __restrict__ mb,
                      __bf16* __restrict__ qs, __bf16* __restrict__ kst, __bf16* __restrict__ vnd) {
    __shared__ __bf16 at[128 * 40];   // y tile [128 n][32 c], stride 40 (pad: 2-way banks)
    __shared__ __bf16 bt[128 * 40];   // w tile [128 o][32 c]
    const int nt = blockIdx.x, ot = blockIdx.y, b = blockIdx.z;
    const int tid = threadIdx.x;
    const int wave = tid >> 6, lane = tid & 63, ln = lane & 15, quad = lane >> 4;
    const int wm = (wave & 1) * 64, wn = (wave >> 1) * 64;
    floatx4 acc[4][4];
#pragma unroll
    for (int i = 0; i < 4; i++)
#pragma unroll
        for (int j = 0; j < 4; j++) acc[i][j] = 0.f;
    const __bf16* ysrc = y + ((size_t)b * NN + nt * 128) * NC;
    const __bf16* wsrc = wb + (size_t)ot * 128 * NC;
    for (int ko = 0; ko < 8; ko++) {
        __syncthreads();
#pragma unroll
        for (int t2 = 0; t2 < 2; t2++) {
            int ch = tid + t2 * 256;
            int row = ch >> 2, cw = ch & 3;
            *(bf16x8*)(at + row * 40 + cw * 8) = *(const bf16x8*)(ysrc + (size_t)row * NC + ko * 32 + cw * 8);
            *(bf16x8*)(bt + row * 40 + cw * 8) = *(const bf16x8*)(wsrc + (size_t)row * NC + ko * 32 + cw * 8);
        }
        __syncthreads();
        bf16x8 af[4], bfr[4];
#pragma unroll
        for (int ii = 0; ii < 4; ii++) af[ii]  = *(const bf16x8*)(at + (wm + ii * 16 + ln) * 40 + quad * 8);
#pragma unroll
        for (int jj = 0; jj < 4; jj++) bfr[jj] = *(const bf16x8*)(bt + (wn + jj * 16 + ln) * 40 + quad * 8);
#pragma unroll
        for (int ii = 0; ii < 4; ii++)
#pragma unroll
            for (int jj = 0; jj < 4; jj++)
                acc[ii][jj] = __builtin_amdgcn_mfma_f32_16x16x32_bf16(af[ii], bfr[jj], acc[ii][jj], 0, 0, 0);
    }
    // epilogue: C element (row n = wm+ii*16+quad*4+r, col o = wn+jj*16+ln)
#pragma unroll
    for (int ii = 0; ii < 4; ii++)
#pragma unroll
        for (int jj = 0; jj < 4; jj++) {
            int o_g = ot * 128 + wn + jj * 16 + ln;
#pragma unroll
            for (int r = 0; r < 4; r++) {
                int n_g = nt * 128 + wm + ii * 16 + quad * 4 + r;
                int hp = n_g >> 6, wp = n_g & 63;
                float val = acc[ii][jj][r] + bqkv[o_g];
                if (ot < 2) {         // Q: PE + FiLM + fold softmax scale
                    val += peqh[o_g * 64 + hp] + peqw[o_g * 64 + wp];
                    val = val * mm[b * NF + o_g] + mb[b * NF + o_g];
                    val *= QSCALE;
                    qs[(((size_t)b * NH + (o_g >> 5)) * NN + n_g) * HSZ + (o_g & 31)] = (__bf16)val;
                } else if (ot < 4) {  // K: PE
                    int c = o_g - 256;
                    val += pekh[c * 64 + hp] + pekw[c * 64 + wp];
                    kst[(((size_t)b * NH + (c >> 5)) * NN + n_g) * HSZ + (c & 31)] = (__bf16)val;
                } else {              // V
                    int c = o_g - 512;
                    vnd[(((size_t)b * NH + (c >> 5)) * NN + n_g) * HSZ + (c & 31)] = (__bf16)val;
                }
            }
        }
}

// ---------------- K3: V transpose [bh][n][32] -> [bh][32][n] ----------------
__global__ void k_vtrans(const __bf16* __restrict__ vnd, __bf16* __restrict__ vdm) {
    int cid = blockIdx.x * 256 + threadIdx.x;   // 262144 chunks of bf16x8
    int mrow = cid >> 2;
    int dg = (cid & 3) * 8;
    int bh = mrow >> 12, m = mrow & 4095;
    bf16x8 v = *(const bf16x8*)(vnd + (size_t)cid * 8);
#pragma unroll
    for (int j = 0; j < 8; j++)
        vdm[((size_t)bh * HSZ + dg + j) * NN + m] = v[j];   // same-line lanes merge in coalescer
}

// ---------------- K4: flash attention ----------------
__launch_bounds__(256)
__global__ void k_attn(const __bf16* __restrict__ qs, const __bf16* __restrict__ ksrc,
                       const __bf16* __restrict__ vdm, const float* __restrict__ ppb,
                       __bf16* __restrict__ attn) {
    __shared__ __bf16 kt[128 * 40];       // K tile [128 m][32 d]
    __shared__ __bf16 vt[32 * 136];       // V tile [32 d][128 m]
    __shared__ __bf16 pt[4][32 * 136];    // per-wave P tile [32 n][128 m]
    int bi = blockIdx.x;
    int xcd = bi & 7, slot = bi >> 3;
    int bh = xcd * 2 + (slot & 1);        // XCD owns 2 (b,h) pairs -> K/V live in its L2
    int qt = slot >> 1;
    int tid = threadIdx.x, wave = tid >> 6, lane = tid & 63, ln = lane & 15, quad = lane >> 4;
    int n0 = qt * 128 + wave * 32;
    const __bf16* qbase = qs + (size_t)bh * NN * HSZ;
    const __bf16* kbase = ksrc + (size_t)bh * NN * HSZ;
    const __bf16* vbase = vdm + (size_t)bh * HSZ * NN;
    bf16x8 qa[2];
#pragma unroll
    for (int i = 0; i < 2; i++)
        qa[i] = *(const bf16x8*)(qbase + (size_t)(n0 + i * 16 + ln) * HSZ + quad * 8);
    floatx4 o[2][2], mI[2], lI[2];
#pragma unroll
    for (int i = 0; i < 2; i++) {
        o[i][0] = 0.f; o[i][1] = 0.f;
        mI[i] = -1e30f; lI[i] = 0.f;
    }
    __bf16* ptw = &pt[wave][0];
    floatx4 zf = 0.f;

    for (int mt = 0; mt < 32; mt++) {
        __syncthreads();
#pragma unroll
        for (int t2 = 0; t2 < 2; t2++) {
            int ch = tid + t2 * 256;
            { int row = ch >> 2, cw = ch & 3;
              *(bf16x8*)(kt + row * 40 + cw * 8) =
                  *(const bf16x8*)(kbase + (size_t)(mt * 128 + row) * HSZ + cw * 8); }
            { int d = ch >> 4, cm = ch & 15;
              *(bf16x8*)(vt + d * 136 + cm * 8) =
                  *(const bf16x8*)(vbase + (size_t)d * NN + mt * 128 + cm * 8); }
        }
        __syncthreads();
        // S = Q K^T (already in log2 domain via QSCALE)
        floatx4 s[2][8];
#pragma unroll
        for (int j = 0; j < 8; j++) {
            bf16x8 kb = *(const bf16x8*)(kt + (j * 16 + ln) * 40 + quad * 8);
            s[0][j] = __builtin_amdgcn_mfma_f32_16x16x32_bf16(qa[0], kb, zf, 0, 0, 0);
            s[1][j] = __builtin_amdgcn_mfma_f32_16x16x32_bf16(qa[1], kb, zf, 0, 0, 0);
        }
        // online softmax; rows owned per (quad, r), reduce over 16 lanes of quad
#pragma unroll
        for (int i = 0; i < 2; i++) {
            floatx4 mx = s[i][0];
#pragma unroll
            for (int j = 1; j < 8; j++)
#pragma unroll
                for (int r = 0; r < 4; r++) mx[r] = fmaxf(mx[r], s[i][j][r]);
#pragma unroll
            for (int off = 1; off < 16; off <<= 1)
#pragma unroll
                for (int r = 0; r < 4; r++) mx[r] = fmaxf(mx[r], __shfl_xor(mx[r], off, 64));
            floatx4 mnew, alpha, rs;
#pragma unroll
            for (int r = 0; r < 4; r++) {
                mnew[r] = fmaxf(mI[i][r], mx[r]);
                alpha[r] = exp2f(mI[i][r] - mnew[r]);
                rs[r] = 0.f;
            }
#pragma unroll
            for (int j = 0; j < 8; j++)
#pragma unroll
                for (int r = 0; r < 4; r++) {
                    float p = exp2f(s[i][j][r] - mnew[r]);
                    s[i][j][r] = p;
                    rs[r] += p;
                }
            // P -> LDS (C-layout -> A-layout transform)
#pragma unroll
            for (int j = 0; j < 8; j++)
#pragma unroll
                for (int r = 0; r < 4; r++)
                    ptw[(i * 16 + quad * 4 + r) * 136 + j * 16 + ln] = (__bf16)s[i][j][r];
#pragma unroll
            for (int off = 1; off < 16; off <<= 1)
#pragma unroll
                for (int r = 0; r < 4; r++) rs[r] += __shfl_xor(rs[r], off, 64);
#pragma unroll
            for (int r = 0; r < 4; r++) {
                lI[i][r] = lI[i][r] * alpha[r] + rs[r];
                mI[i][r] = mnew[r];
                o[i][0][r] *= alpha[r];
                o[i][1][r] *= alpha[r];
            }
        }
        __asm__ volatile("s_waitcnt lgkmcnt(0)" ::: "memory");  // P writes visible to own-wave reads
        // O += P V^T
#pragma unroll
        for (int k2 = 0; k2 < 4; k2++) {
            bf16x8 vb0 = *(const bf16x8*)(vt + ln * 136 + k2 * 32 + quad * 8);
            bf16x8 vb1 = *(const bf16x8*)(vt + (16 + ln) * 136 + k2 * 32 + quad * 8);
#pragma unroll
            for (int i = 0; i < 2; i++) {
                bf16x8 pa = *(const bf16x8*)(ptw + (i * 16 + ln) * 136 + k2 * 32 + quad * 8);
                o[i][0] = __builtin_amdgcn_mfma_f32_16x16x32_bf16(pa, vb0, o[i][0], 0, 0, 0);
                o[i][1] = __builtin_amdgcn_mfma_f32_16x16x32_bf16(pa, vb1, o[i][1], 0, 0, 0);
            }
        }
    }
    // epilogue: normalize, add pre_proj_bias, store attn [b][n][f]
    int b = bh >> 3, h = bh & 7;
#pragma unroll
    for (int i = 0; i < 2; i++) {
        floatx4 inv;
#pragma unroll
        for (int r = 0; r < 4; r++) inv[r] = 1.f / lI[i][r];
#pragma unroll
        for (int dj = 0; dj < 2; dj++)
#pragma unroll
            for (int r = 0; r < 4; r++) {
                int n_g = n0 + i * 16 + quad * 4 + r;
                int f = h * HSZ + dj * 16 + ln;
                float val = o[i][dj][r] * inv[r] + ppb[f];
                attn[((size_t)b * NN + n_g) * NF + f] = (__bf16)val;
            }
    }
}

// ---------------- K5: proj GEMM out[o,n] + residual ----------------
__launch_bounds__(256)
__global__ void k_proj(const __bf16* __restrict__ attn, const __bf16* __restrict__ wpb,
                       const float* __restrict__ x, const float* __restrict__ idsc,
                       float* __restrict__ out) {
    __shared__ __bf16 at[64 * 40];    // w_proj tile [64 o][32 f]
    __shared__ __bf16 bt[128 * 40];   // attn tile [128 n][32 f]
    int nt = blockIdx.x, ot = blockIdx.y, b = blockIdx.z;
    int tid = threadIdx.x, wave = tid >> 6, lane = tid & 63, ln = lane & 15, quad = lane >> 4;
    int wo = (wave & 1) * 32, wn = (wave >> 1) * 64;
    floatx4 acc[2][4];
#pragma unroll
    for (int i = 0; i < 2; i++)
#pragma unroll
        for (int j = 0; j < 4; j++) acc[i][j] = 0.f;
    const __bf16* asrc = wpb + (size_t)ot * 64 * NF;
    const __bf16* bsrc = attn + ((size_t)b * NN + nt * 128) * NF;
    for (int ko = 0; ko < 8; ko++) {
        __syncthreads();
        { int row = tid >> 2, cw = tid & 3;
          *(bf16x8*)(at + row * 40 + cw * 8) = *(const bf16x8*)(asrc + (size_t)row * NF + ko * 32 + cw * 8); }
#pragma unroll
        for (int t2 = 0; t2 < 2; t2++) {
            int ch = tid + t2 * 256;
            int row = ch >> 2, cw = ch & 3;
            *(bf16x8*)(bt + row * 40 + cw * 8) = *(const bf16x8*)(bsrc + (size_t)row * NF + ko * 32 + cw * 8);
        }
        __syncthreads();
        bf16x8 af[2], bfr[4];
#pragma unroll
        for (int oi = 0; oi < 2; oi++) af[oi]  = *(const bf16x8*)(at + (wo + oi * 16 + ln) * 40 + quad * 8);
#pragma unroll
        for (int nj = 0; nj < 4; nj++) bfr[nj] = *(const bf16x8*)(bt + (wn + nj * 16 + ln) * 40 + quad * 8);
#pragma unroll
        for (int oi = 0; oi < 2; oi++)
#pragma unroll
            for (int nj = 0; nj < 4; nj++)
                acc[oi][nj] = __builtin_amdgcn_mfma_f32_16x16x32_bf16(af[oi], bfr[nj], acc[oi][nj], 0, 0, 0);
    }
#pragma unroll
    for (int oi = 0; oi < 2; oi++)
#pragma unroll
        for (int nj = 0; nj < 4; nj++)
#pragma unroll
            for (int r = 0; r < 4; r++) {
                int o_g = ot * 64 + wo + oi * 16 + quad * 4 + r;
                int n_g = nt * 128 + wn + nj * 16 + ln;
                size_t idx = ((size_t)b * NF + o_g) * NN + n_g;
                out[idx] = x[idx] * idsc[o_g] + acc[oi][nj][r];
            }
}

// ---------------- launcher ----------------
extern "C" void kernel_launch(void* const* d_in, const int* in_sizes, int n_in,
                              void* d_out, int out_size, void* d_ws, size_t ws_size,
                              hipStream_t stream) {
    (void)in_sizes; (void)n_in; (void)out_size; (void)ws_size;
    const float* x    = (const float*)d_in[0];
    const float* mm   = (const float*)d_in[1];
    const float* mb   = (const float*)d_in[2];
    const float* wqkv = (const float*)d_in[3];
    const float* bqkv = (const float*)d_in[4];
    const float* wproj= (const float*)d_in[5];
    const float* peqh = (const float*)d_in[6];
    const float* peqw = (const float*)d_in[7];
    const float* pekh = (const float*)d_in[8];
    const float* pekw = (const float*)d_in[9];
    const float* pab  = (const float*)d_in[10];
    const float* pqb  = (const float*)d_in[11];
    const float* ppb  = (const float*)d_in[12];
    const float* idsc = (const float*)d_in[13];
    float* out = (float*)d_out;

    __bf16* ws = (__bf16*)d_ws;
    const size_t SEG = 2097152;            // elements per big buffer
    __bf16* y    = ws;
    __bf16* qs   = ws + SEG;
    __bf16* kst  = ws + SEG * 2;
    __bf16* vnd  = ws + SEG * 3;
    __bf16* vdm  = ws + SEG * 4;
    __bf16* attn = ws + SEG * 5;
    __bf16* wqb  = ws + SEG * 6;
    __bf16* wpb  = wqb + 196608;           // total ~25.7 MB

    hipLaunchKernelGGL(k_convert_w, dim3(1024), dim3(256), 0, stream, wqkv, wproj, wqb, wpb);
    hipLaunchKernelGGL(k_preact,    dim3(2048), dim3(256), 0, stream, x, pab, pqb, y);
    hipLaunchKernelGGL(k_qkv,       dim3(32, 6, 2), dim3(256), 0, stream,
                       y, wqb, bqkv, peqh, peqw, pekh, pekw, mm, mb, qs, kst, vnd);
    hipLaunchKernelGGL(k_vtrans,    dim3(1024), dim3(256), 0, stream, vnd, vdm);
    hipLaunchKernelGGL(k_attn,      dim3(512), dim3(256), 0, stream, qs, kst, vdm, ppb, attn);
    hipLaunchKernelGGL(k_proj,      dim3(32, 4, 2), dim3(256), 0, stream, attn, wpb, x, idsc, out);
}

// Round 2
// 223.986 us; speedup vs baseline: 1.4161x; 1.4161x over previous
//
#include <hip/hip_runtime.h>
#include <hip/hip_bf16.h>
#include <cstdint>

// Problem constants
#define NB   2
#define NC   256
#define NN   4096   // H*W = 64*64
#define NH   8      // heads
#define HSZ  32     // head size
#define NF   256    // FEAT
#define N3F  768

typedef __bf16 bf16x8 __attribute__((ext_vector_type(8)));
typedef __bf16 bf16x4 __attribute__((ext_vector_type(4)));
typedef short  s16x4  __attribute__((ext_vector_type(4)));
typedef float  floatx4 __attribute__((ext_vector_type(4)));

// log2(e)/sqrt(32): folded into q so softmax runs in exp2 domain
#define QSCALE 0.25506601622184f

// ---------------- K0: convert weights to bf16 ----------------
__global__ void k_convert_w(const float* __restrict__ wqkv, const float* __restrict__ wproj,
                            __bf16* __restrict__ wqb, __bf16* __restrict__ wpb) {
    int i = blockIdx.x * 256 + threadIdx.x;   // 262144 total
    if (i < 196608) wqb[i] = (__bf16)wqkv[i];
    else            wpb[i - 196608] = (__bf16)wproj[i - 196608];
}

// ---------------- K1: preact silu, store y as [b][n][c] bf16 ----------------
__global__ void k_preact(const float* __restrict__ x, const float* __restrict__ pab,
                         const float* __restrict__ pqb, __bf16* __restrict__ y) {
    int t = blockIdx.x * 256 + threadIdx.x;   // 524288 threads, 4 elems each
    int base = t * 4;                          // linear over [b][c][n]
    int c = (base >> 12) & 255;
    int b = base >> 20;
    int n = base & 4095;
    const float4 xv = *(const float4*)(x + base);
    float bias = pab[c], qb = pqb[c];
    float vs[4] = {xv.x, xv.y, xv.z, xv.w};
    __bf16* yb = y + ((size_t)b * NN) * NC + c;
#pragma unroll
    for (int i = 0; i < 4; i++) {
        float s = vs[i] + bias;
        float r = s / (1.f + __expf(-s)) + qb;   // silu + pre_qkv_bias
        yb[(size_t)(n + i) * NC] = (__bf16)r;    // scattered bf16 write, L2-absorbed
    }
}

// ---------------- K2: QKV GEMM out[n,o] = y_nc * w_qkv^T + epilogue ----------------
__launch_bounds__(256)
__global__ void k_qkv(const __bf16* __restrict__ y, const __bf16* __restrict__ wb,
                      const float* __restrict__ bqkv,
                      const float* __restrict__ peqh, const float* __restrict__ peqw,
                      const float* __restrict__ pekh, const float* __restrict__ pekw,
                      const float* __restrict__ mm, const float* __restrict__ mb,
                      __bf16* __restrict__ qs, __bf16* __restrict__ kst, __bf16* __restrict__ vnd) {
    __shared__ __bf16 at[128 * 40];   // y tile [128 n][32 c], stride 40
    __shared__ __bf16 bt[128 * 40];   // w tile [128 o][32 c]
    const int nt = blockIdx.x, ot = blockIdx.y, b = blockIdx.z;
    const int tid = threadIdx.x;
    const int wave = tid >> 6, lane = tid & 63, ln = lane & 15, quad = lane >> 4;
    const int wm = (wave & 1) * 64, wn = (wave >> 1) * 64;
    floatx4 acc[4][4];
#pragma unroll
    for (int i = 0; i < 4; i++)
#pragma unroll
        for (int j = 0; j < 4; j++) acc[i][j] = 0.f;
    const __bf16* ysrc = y + ((size_t)b * NN + nt * 128) * NC;
    const __bf16* wsrc = wb + (size_t)ot * 128 * NC;
    for (int ko = 0; ko < 8; ko++) {
        __syncthreads();
#pragma unroll
        for (int t2 = 0; t2 < 2; t2++) {
            int ch = tid + t2 * 256;
            int row = ch >> 2, cw = ch & 3;
            *(bf16x8*)(at + row * 40 + cw * 8) = *(const bf16x8*)(ysrc + (size_t)row * NC + ko * 32 + cw * 8);
            *(bf16x8*)(bt + row * 40 + cw * 8) = *(const bf16x8*)(wsrc + (size_t)row * NC + ko * 32 + cw * 8);
        }
        __syncthreads();
        bf16x8 af[4], bfr[4];
#pragma unroll
        for (int ii = 0; ii < 4; ii++) af[ii]  = *(const bf16x8*)(at + (wm + ii * 16 + ln) * 40 + quad * 8);
#pragma unroll
        for (int jj = 0; jj < 4; jj++) bfr[jj] = *(const bf16x8*)(bt + (wn + jj * 16 + ln) * 40 + quad * 8);
#pragma unroll
        for (int ii = 0; ii < 4; ii++)
#pragma unroll
            for (int jj = 0; jj < 4; jj++)
                acc[ii][jj] = __builtin_amdgcn_mfma_f32_16x16x32_bf16(af[ii], bfr[jj], acc[ii][jj], 0, 0, 0);
    }
    // epilogue: C element (row n = wm+ii*16+quad*4+r, col o = wn+jj*16+ln)
#pragma unroll
    for (int ii = 0; ii < 4; ii++)
#pragma unroll
        for (int jj = 0; jj < 4; jj++) {
            int o_g = ot * 128 + wn + jj * 16 + ln;
#pragma unroll
            for (int r = 0; r < 4; r++) {
                int n_g = nt * 128 + wm + ii * 16 + quad * 4 + r;
                int hp = n_g >> 6, wp = n_g & 63;
                float val = acc[ii][jj][r] + bqkv[o_g];
                if (ot < 2) {         // Q: PE + FiLM + fold softmax scale
                    val += peqh[o_g * 64 + hp] + peqw[o_g * 64 + wp];
                    val = val * mm[b * NF + o_g] + mb[b * NF + o_g];
                    val *= QSCALE;
                    qs[(((size_t)b * NH + (o_g >> 5)) * NN + n_g) * HSZ + (o_g & 31)] = (__bf16)val;
                } else if (ot < 4) {  // K: PE
                    int c = o_g - 256;
                    val += pekh[c * 64 + hp] + pekw[c * 64 + wp];
                    kst[(((size_t)b * NH + (c >> 5)) * NN + n_g) * HSZ + (c & 31)] = (__bf16)val;
                } else {              // V
                    int c = o_g - 512;
                    vnd[(((size_t)b * NH + (c >> 5)) * NN + n_g) * HSZ + (c & 31)] = (__bf16)val;
                }
            }
        }
}

// ---------------- K3: V transpose [bh][n][32] -> [bh][32][n] ----------------
__global__ void k_vtrans(const __bf16* __restrict__ vnd, __bf16* __restrict__ vdm) {
    int cid = blockIdx.x * 256 + threadIdx.x;   // 262144 chunks of bf16x8
    int mrow = cid >> 2;
    int dg = (cid & 3) * 8;
    int bh = mrow >> 12, m = mrow & 4095;
    bf16x8 v = *(const bf16x8*)(vnd + (size_t)cid * 8);
#pragma unroll
    for (int j = 0; j < 8; j++)
        vdm[((size_t)bh * HSZ + dg + j) * NN + m] = v[j];
}

// ---------------- K4: flash attention (S^T trick, max-free softmax) ----------------
// Per wave: 16 q-rows. S^T = mfma16x16x32(K_frag, Q_frag) puts P^T... rather puts
// S^T in C-layout (col = n = lane&15, row = m = quad*4+reg) which IS the A-operand
// layout of mfma_f32_16x16x16_bf16 (i = lane&15, k = quad*4+elem). So exp2'd P feeds
// the PV MFMA straight from registers: no LDS P-transform, no bank conflicts.
__launch_bounds__(256)
__global__ void k_attn(const __bf16* __restrict__ qs, const __bf16* __restrict__ ksrc,
                       const __bf16* __restrict__ vdm, const float* __restrict__ ppb,
                       __bf16* __restrict__ attn) {
    __shared__ __bf16 kt[128 * 40];       // K tile [128 m][32 d], pad->2-way banks (free)
    __shared__ __bf16 vt[32 * 136];       // V tile [32 d][128 m]
    int bi = blockIdx.x;                  // 1024 blocks
    int xcd = bi & 7, slot = bi >> 3;
    int bh = xcd * 2 + (slot & 1);        // XCD owns 2 (b,h) pairs -> K/V in its L2
    int qt = slot >> 1;                   // 64 q-tiles of 64 rows
    int tid = threadIdx.x, wave = tid >> 6, lane = tid & 63, ln = lane & 15, quad = lane >> 4;
    int n0 = qt * 64 + wave * 16;
    const __bf16* qbase = qs + (size_t)bh * NN * HSZ;
    const __bf16* kbase = ksrc + (size_t)bh * NN * HSZ;
    const __bf16* vbase = vdm + (size_t)bh * HSZ * NN;
    // Q fragment (B-operand): row n = ln, k(d) = quad*8..quad*8+7
    bf16x8 qa = *(const bf16x8*)(qbase + (size_t)(n0 + ln) * HSZ + quad * 8);
    floatx4 o0 = 0.f, o1 = 0.f;           // O block: n = quad*4+reg, d = dj*16+ln
    float lsum = 0.f;                      // row-sum partial for n = ln (this quad's m's)
    floatx4 zf = 0.f;

    for (int mt = 0; mt < 32; mt++) {
        __syncthreads();
#pragma unroll
        for (int t2 = 0; t2 < 2; t2++) {
            int ch = tid + t2 * 256;
            { int row = ch >> 2, cw = ch & 3;
              *(bf16x8*)(kt + row * 40 + cw * 8) =
                  *(const bf16x8*)(kbase + (size_t)(mt * 128 + row) * HSZ + cw * 8); }
            { int d = ch >> 4, cm = ch & 15;
              *(bf16x8*)(vt + d * 136 + cm * 8) =
                  *(const bf16x8*)(vbase + (size_t)d * NN + mt * 128 + cm * 8); }
        }
        __syncthreads();
#pragma unroll
        for (int j = 0; j < 8; j++) {
            // S^T block: A = K rows (m = j*16+ln), B = Q rows
            bf16x8 kb = *(const bf16x8*)(kt + (j * 16 + ln) * 40 + quad * 8);
            floatx4 s = __builtin_amdgcn_mfma_f32_16x16x32_bf16(kb, qa, zf, 0, 0, 0);
            // exp2 (log2-domain logits via QSCALE); accumulate row-sum for col n = ln
            bf16x4 p;
#pragma unroll
            for (int r = 0; r < 4; r++) {
                float e = __builtin_amdgcn_exp2f(s[r]);
                lsum += e;
                p[r] = (__bf16)e;
            }
            s16x4 pa;
            __builtin_memcpy(&pa, &p, 8);
            // V fragments (B-operand of 16x16x16): row d = dj*16+ln, k(m) = quad*4..+3
            s16x4 vb0, vb1;
            __builtin_memcpy(&vb0, (const __bf16*)(vt + ln * 136 + j * 16 + quad * 4), 8);
            __builtin_memcpy(&vb1, (const __bf16*)(vt + (16 + ln) * 136 + j * 16 + quad * 4), 8);
            o0 = __builtin_amdgcn_mfma_f32_16x16x16bf16_1k(pa, vb0, o0, 0, 0, 0);
            o1 = __builtin_amdgcn_mfma_f32_16x16x16bf16_1k(pa, vb1, o1, 0, 0, 0);
        }
    }
    // reduce row-sums across quads: after this every lane holds l for n = ln
    lsum += __shfl_xor(lsum, 16, 64);
    lsum += __shfl_xor(lsum, 32, 64);
    // epilogue: O rows are n = quad*4+r -> fetch l from lane (quad*4+r)
    int b = bh >> 3, h = bh & 7;
#pragma unroll
    for (int r = 0; r < 4; r++) {
        float l_r = __shfl(lsum, quad * 4 + r, 64);
        float inv = 1.f / l_r;
        int n_g = n0 + quad * 4 + r;
#pragma unroll
        for (int dj = 0; dj < 2; dj++) {
            int f = h * HSZ + dj * 16 + ln;
            float val = (dj ? o1[r] : o0[r]) * inv + ppb[f];
            attn[((size_t)b * NN + n_g) * NF + f] = (__bf16)val;
        }
    }
}

// ---------------- K5: proj GEMM out[o,n] + residual ----------------
__launch_bounds__(256)
__global__ void k_proj(const __bf16* __restrict__ attn, const __bf16* __restrict__ wpb,
                       const float* __restrict__ x, const float* __restrict__ idsc,
                       float* __restrict__ out) {
    __shared__ __bf16 at[64 * 40];    // w_proj tile [64 o][32 f]
    __shared__ __bf16 bt[128 * 40];   // attn tile [128 n][32 f]
    int nt = blockIdx.x, ot = blockIdx.y, b = blockIdx.z;
    int tid = threadIdx.x, wave = tid >> 6, lane = tid & 63, ln = lane & 15, quad = lane >> 4;
    int wo = (wave & 1) * 32, wn = (wave >> 1) * 64;
    floatx4 acc[2][4];
#pragma unroll
    for (int i = 0; i < 2; i++)
#pragma unroll
        for (int j = 0; j < 4; j++) acc[i][j] = 0.f;
    const __bf16* asrc = wpb + (size_t)ot * 64 * NF;
    const __bf16* bsrc = attn + ((size_t)b * NN + nt * 128) * NF;
    for (int ko = 0; ko < 8; ko++) {
        __syncthreads();
        { int row = tid >> 2, cw = tid & 3;
          *(bf16x8*)(at + row * 40 + cw * 8) = *(const bf16x8*)(asrc + (size_t)row * NF + ko * 32 + cw * 8); }
#pragma unroll
        for (int t2 = 0; t2 < 2; t2++) {
            int ch = tid + t2 * 256;
            int row = ch >> 2, cw = ch & 3;
            *(bf16x8*)(bt + row * 40 + cw * 8) = *(const bf16x8*)(bsrc + (size_t)row * NF + ko * 32 + cw * 8);
        }
        __syncthreads();
        bf16x8 af[2], bfr[4];
#pragma unroll
        for (int oi = 0; oi < 2; oi++) af[oi]  = *(const bf16x8*)(at + (wo + oi * 16 + ln) * 40 + quad * 8);
#pragma unroll
        for (int nj = 0; nj < 4; nj++) bfr[nj] = *(const bf16x8*)(bt + (wn + nj * 16 + ln) * 40 + quad * 8);
#pragma unroll
        for (int oi = 0; oi < 2; oi++)
#pragma unroll
            for (int nj = 0; nj < 4; nj++)
                acc[oi][nj] = __builtin_amdgcn_mfma_f32_16x16x32_bf16(af[oi], bfr[nj], acc[oi][nj], 0, 0, 0);
    }
#pragma unroll
    for (int oi = 0; oi < 2; oi++)
#pragma unroll
        for (int nj = 0; nj < 4; nj++)
#pragma unroll
            for (int r = 0; r < 4; r++) {
                int o_g = ot * 64 + wo + oi * 16 + quad * 4 + r;
                int n_g = nt * 128 + wn + nj * 16 + ln;
                size_t idx = ((size_t)b * NF + o_g) * NN + n_g;
                out[idx] = x[idx] * idsc[o_g] + acc[oi][nj][r];
            }
}

// ---------------- launcher ----------------
extern "C" void kernel_launch(void* const* d_in, const int* in_sizes, int n_in,
                              void* d_out, int out_size, void* d_ws, size_t ws_size,
                              hipStream_t stream) {
    (void)in_sizes; (void)n_in; (void)out_size; (void)ws_size;
    const float* x    = (const float*)d_in[0];
    const float* mm   = (const float*)d_in[1];
    const float* mb   = (const float*)d_in[2];
    const float* wqkv = (const float*)d_in[3];
    const float* bqkv = (const float*)d_in[4];
    const float* wproj= (const float*)d_in[5];
    const float* peqh = (const float*)d_in[6];
    const float* peqw = (const float*)d_in[7];
    const float* pekh = (const float*)d_in[8];
    const float* pekw = (const float*)d_in[9];
    const float* pab  = (const float*)d_in[10];
    const float* pqb  = (const float*)d_in[11];
    const float* ppb  = (const float*)d_in[12];
    const float* idsc = (const float*)d_in[13];
    float* out = (float*)d_out;

    __bf16* ws = (__bf16*)d_ws;
    const size_t SEG = 2097152;            // elements per big buffer
    __bf16* y    = ws;
    __bf16* qs   = ws + SEG;
    __bf16* kst  = ws + SEG * 2;
    __bf16* vnd  = ws + SEG * 3;
    __bf16* vdm  = ws + SEG * 4;
    __bf16* attn = ws + SEG * 5;
    __bf16* wqb  = ws + SEG * 6;
    __bf16* wpb  = wqb + 196608;           // total ~25.7 MB

    hipLaunchKernelGGL(k_convert_w, dim3(1024), dim3(256), 0, stream, wqkv, wproj, wqb, wpb);
    hipLaunchKernelGGL(k_preact,    dim3(2048), dim3(256), 0, stream, x, pab, pqb, y);
    hipLaunchKernelGGL(k_qkv,       dim3(32, 6, 2), dim3(256), 0, stream,
                       y, wqb, bqkv, peqh, peqw, pekh, pekw, mm, mb, qs, kst, vnd);
    hipLaunchKernelGGL(k_vtrans,    dim3(1024), dim3(256), 0, stream, vnd, vdm);
    hipLaunchKernelGGL(k_attn,      dim3(1024), dim3(256), 0, stream, qs, kst, vdm, ppb, attn);
    hipLaunchKernelGGL(k_proj,      dim3(32, 4, 2), dim3(256), 0, stream, attn, wpb, x, idsc, out);
}

// Round 3
// 205.024 us; speedup vs baseline: 1.5471x; 1.0925x over previous
//
#include <hip/hip_runtime.h>
#include <hip/hip_bf16.h>
#include <cstdint>

// Problem constants
#define NB   2
#define NC   256
#define NN   4096   // H*W = 64*64
#define NH   8      // heads
#define HSZ  32     // head size
#define NF   256    // FEAT
#define N3F  768

typedef __bf16 bf16x8 __attribute__((ext_vector_type(8)));
typedef __bf16 bf16x4 __attribute__((ext_vector_type(4)));
typedef short  s16x4  __attribute__((ext_vector_type(4)));
typedef float  floatx4 __attribute__((ext_vector_type(4)));

// log2(e)/sqrt(32): folded into q so softmax runs in exp2 domain
#define QSCALE 0.25506601622184f

// ---------------- K0: convert weights to bf16 ----------------
__global__ void k_convert_w(const float* __restrict__ wqkv, const float* __restrict__ wproj,
                            __bf16* __restrict__ wqb, __bf16* __restrict__ wpb) {
    int i = blockIdx.x * 256 + threadIdx.x;   // 262144 total
    if (i < 196608) wqb[i] = (__bf16)wqkv[i];
    else            wpb[i - 196608] = (__bf16)wproj[i - 196608];
}

// ---------------- K1: preact silu, store y as [b][n][c] bf16 (LDS transpose) ------
// Block: 32 n-rows x 256 c. Reads x[c][n] float4 coalesced, writes y[n][c] bf16x8.
__global__ void k_preact(const float* __restrict__ x, const float* __restrict__ pab,
                         const float* __restrict__ pqb, __bf16* __restrict__ y) {
    __shared__ __bf16 ct[32 * 264];           // [n][c], stride 264
    int b = blockIdx.x >> 7, nt = blockIdx.x & 127;
    int n0 = nt * 32;
    int tid = threadIdx.x;
    int cbase = tid >> 3, nc = tid & 7;       // n-chunk nc covers 4 n
#pragma unroll
    for (int q = 0; q < 8; q++) {
        int c = cbase + q * 32;
        const float4 xv = *(const float4*)(x + ((size_t)b * NC + c) * NN + n0 + nc * 4);
        float bias = pab[c], qb = pqb[c];
        float vs[4] = {xv.x, xv.y, xv.z, xv.w};
#pragma unroll
        for (int i = 0; i < 4; i++) {
            float s = vs[i] + bias;
            float r = s / (1.f + __expf(-s)) + qb;   // silu + pre_qkv_bias
            ct[(nc * 4 + i) * 264 + c] = (__bf16)r;
        }
    }
    __syncthreads();
#pragma unroll
    for (int q = 0; q < 4; q++) {
        int id = tid + q * 256;               // 1024 chunks
        int n = id >> 5, ck = (id & 31) * 8;
        bf16x8 v = *(const bf16x8*)(ct + n * 264 + ck);
        *(bf16x8*)(y + ((size_t)b * NN + n0 + n) * NC + ck) = v;
    }
}

// ---------------- K2: QKV GEMM out[n,o] = y_nc * w_qkv^T + epilogue ----------------
// Epilogue goes through LDS so all global stores are 16B coalesced.
// Q -> qs[bh][n][d], K -> kst[bh][m][d], V -> vdm[bh][d][m] (direct transpose).
__launch_bounds__(256)
__global__ void k_qkv(const __bf16* __restrict__ y, const __bf16* __restrict__ wb,
                      const float* __restrict__ bqkv,
                      const float* __restrict__ peqh, const float* __restrict__ peqw,
                      const float* __restrict__ pekh, const float* __restrict__ pekw,
                      const float* __restrict__ mm, const float* __restrict__ mb,
                      __bf16* __restrict__ qs, __bf16* __restrict__ kst, __bf16* __restrict__ vdm) {
    __shared__ __bf16 at[128 * 40];   // y tile [128 n][32 c]
    __shared__ __bf16 bt[128 * 40];   // w tile [128 o][32 c]
    __shared__ __bf16 ct[128 * 136];  // epilogue transpose buffer
    const int nt = blockIdx.x, ot = blockIdx.y, b = blockIdx.z;
    const int tid = threadIdx.x;
    const int wave = tid >> 6, lane = tid & 63, ln = lane & 15, quad = lane >> 4;
    const int wm = (wave & 1) * 64, wn = (wave >> 1) * 64;
    floatx4 acc[4][4];
#pragma unroll
    for (int i = 0; i < 4; i++)
#pragma unroll
        for (int j = 0; j < 4; j++) acc[i][j] = 0.f;
    const __bf16* ysrc = y + ((size_t)b * NN + nt * 128) * NC;
    const __bf16* wsrc = wb + (size_t)ot * 128 * NC;
    for (int ko = 0; ko < 8; ko++) {
        __syncthreads();
#pragma unroll
        for (int t2 = 0; t2 < 2; t2++) {
            int ch = tid + t2 * 256;
            int row = ch >> 2, cw = ch & 3;
            *(bf16x8*)(at + row * 40 + cw * 8) = *(const bf16x8*)(ysrc + (size_t)row * NC + ko * 32 + cw * 8);
            *(bf16x8*)(bt + row * 40 + cw * 8) = *(const bf16x8*)(wsrc + (size_t)row * NC + ko * 32 + cw * 8);
        }
        __syncthreads();
        bf16x8 af[4], bfr[4];
#pragma unroll
        for (int ii = 0; ii < 4; ii++) af[ii]  = *(const bf16x8*)(at + (wm + ii * 16 + ln) * 40 + quad * 8);
#pragma unroll
        for (int jj = 0; jj < 4; jj++) bfr[jj] = *(const bf16x8*)(bt + (wn + jj * 16 + ln) * 40 + quad * 8);
#pragma unroll
        for (int ii = 0; ii < 4; ii++)
#pragma unroll
            for (int jj = 0; jj < 4; jj++)
                acc[ii][jj] = __builtin_amdgcn_mfma_f32_16x16x32_bf16(af[ii], bfr[jj], acc[ii][jj], 0, 0, 0);
    }
    // epilogue: C element (n_l = wm+ii*16+quad*4+r, o_l = wn+jj*16+ln)
    if (ot < 4) {
        // Q/K: ct[n][o]
#pragma unroll
        for (int ii = 0; ii < 4; ii++)
#pragma unroll
            for (int jj = 0; jj < 4; jj++) {
                int o_l = wn + jj * 16 + ln;
                int o_g = ot * 128 + o_l;
#pragma unroll
                for (int r = 0; r < 4; r++) {
                    int n_l = wm + ii * 16 + quad * 4 + r;
                    int n_g = nt * 128 + n_l;
                    int hp = n_g >> 6, wp = n_g & 63;
                    float val = acc[ii][jj][r] + bqkv[o_g];
                    if (ot < 2) {         // Q: PE + FiLM + fold softmax scale
                        val += peqh[o_g * 64 + hp] + peqw[o_g * 64 + wp];
                        val = val * mm[b * NF + o_g] + mb[b * NF + o_g];
                        val *= QSCALE;
                    } else {              // K: PE
                        int c = o_g - 256;
                        val += pekh[c * 64 + hp] + pekw[c * 64 + wp];
                    }
                    ct[n_l * 136 + o_l] = (__bf16)val;
                }
            }
        __syncthreads();
#pragma unroll
        for (int q = 0; q < 8; q++) {
            int id = tid + q * 256;       // 2048 chunks
            int n_l = id >> 4, oc = (id & 15) * 8;
            bf16x8 v = *(const bf16x8*)(ct + n_l * 136 + oc);
            int n_g = nt * 128 + n_l;
            int o_g = ot * 128 + oc;
            if (ot < 2) {
                int h = o_g >> 5, d = o_g & 31;
                *(bf16x8*)(qs + (((size_t)b * NH + h) * NN + n_g) * HSZ + d) = v;
            } else {
                int c = o_g - 256, h = c >> 5, d = c & 31;
                *(bf16x8*)(kst + (((size_t)b * NH + h) * NN + n_g) * HSZ + d) = v;
            }
        }
    } else {
        // V: ct[o][n] -> vdm[bh][d][m]
#pragma unroll
        for (int ii = 0; ii < 4; ii++)
#pragma unroll
            for (int jj = 0; jj < 4; jj++) {
                int o_l = wn + jj * 16 + ln;
                int o_g = ot * 128 + o_l;
#pragma unroll
                for (int r = 0; r < 4; r++) {
                    int n_l = wm + ii * 16 + quad * 4 + r;
                    float val = acc[ii][jj][r] + bqkv[o_g];
                    ct[o_l * 136 + n_l] = (__bf16)val;
                }
            }
        __syncthreads();
#pragma unroll
        for (int q = 0; q < 8; q++) {
            int id = tid + q * 256;
            int o_l = id >> 4, ncnk = (id & 15) * 8;
            bf16x8 v = *(const bf16x8*)(ct + o_l * 136 + ncnk);
            int c = ot * 128 + o_l - 512, h = c >> 5, d = c & 31;
            *(bf16x8*)(vdm + (((size_t)b * NH + h) * HSZ + d) * NN + nt * 128 + ncnk) = v;
        }
    }
}

// ---------------- K3: flash attention (S^T trick, dbuf staging, 2 q-frags) --------
__launch_bounds__(256)
__global__ void k_attn(const __bf16* __restrict__ qs, const __bf16* __restrict__ ksrc,
                       const __bf16* __restrict__ vdm, const float* __restrict__ ppb,
                       __bf16* __restrict__ attn) {
    __shared__ __bf16 kt[2][128 * 40];    // K tile [m][d]
    __shared__ __bf16 vt[2][32 * 136];    // V tile [d][m]
    int bi = blockIdx.x;                  // 512 blocks
    int xcd = bi & 7, slot = bi >> 3;
    int bh = xcd * 2 + (slot & 1);        // XCD owns 2 (b,h) pairs -> K/V in its L2
    int qt = slot >> 1;                   // 32 q-tiles of 128 rows
    int tid = threadIdx.x, wave = tid >> 6, lane = tid & 63, ln = lane & 15, quad = lane >> 4;
    int n0 = qt * 128 + wave * 32;
    const __bf16* qbase = qs + (size_t)bh * NN * HSZ;
    const __bf16* kbase = ksrc + (size_t)bh * NN * HSZ;
    const __bf16* vbase = vdm + (size_t)bh * HSZ * NN;
    bf16x8 qa[2];
    qa[0] = *(const bf16x8*)(qbase + (size_t)(n0 + ln) * HSZ + quad * 8);
    qa[1] = *(const bf16x8*)(qbase + (size_t)(n0 + 16 + ln) * HSZ + quad * 8);
    floatx4 o[2][2];
    o[0][0] = 0.f; o[0][1] = 0.f; o[1][0] = 0.f; o[1][1] = 0.f;
    float lsum[2] = {0.f, 0.f};
    floatx4 zf = 0.f;
    // staging: thread handles chunks ch0, ch1 (K rows, V rows)
    const int ch0 = tid, ch1 = tid + 256;
    const int k0r = ch0 >> 2, k0c = (ch0 & 3) * 8;
    const int k1r = ch1 >> 2, k1c = (ch1 & 3) * 8;
    const int v0d = ch0 >> 4, v0m = (ch0 & 15) * 8;
    const int v1d = ch1 >> 4, v1m = (ch1 & 15) * 8;
    bf16x8 krg0, krg1, vrg0, vrg1;
    // prologue: load tile 0
    krg0 = *(const bf16x8*)(kbase + (size_t)(0 + k0r) * HSZ + k0c);
    krg1 = *(const bf16x8*)(kbase + (size_t)(0 + k1r) * HSZ + k1c);
    vrg0 = *(const bf16x8*)(vbase + (size_t)v0d * NN + 0 + v0m);
    vrg1 = *(const bf16x8*)(vbase + (size_t)v1d * NN + 0 + v1m);

    for (int mt = 0; mt < 32; mt++) {
        int buf = mt & 1;
        // commit staged registers to LDS (safe: all waves passed barrier(mt-1))
        *(bf16x8*)(&kt[buf][k0r * 40 + k0c]) = krg0;
        *(bf16x8*)(&kt[buf][k1r * 40 + k1c]) = krg1;
        *(bf16x8*)(&vt[buf][v0d * 136 + v0m]) = vrg0;
        *(bf16x8*)(&vt[buf][v1d * 136 + v1m]) = vrg1;
        __syncthreads();                  // single barrier per tile
        if (mt < 31) {                    // async prefetch next tile (in flight during compute)
            int m1 = (mt + 1) * 128;
            krg0 = *(const bf16x8*)(kbase + (size_t)(m1 + k0r) * HSZ + k0c);
            krg1 = *(const bf16x8*)(kbase + (size_t)(m1 + k1r) * HSZ + k1c);
            vrg0 = *(const bf16x8*)(vbase + (size_t)v0d * NN + m1 + v0m);
            vrg1 = *(const bf16x8*)(vbase + (size_t)v1d * NN + m1 + v1m);
        }
        const __bf16* ktb = &kt[buf][0];
        const __bf16* vtb = &vt[buf][0];
#pragma unroll
        for (int j = 0; j < 8; j++) {
            bf16x8 kb = *(const bf16x8*)(ktb + (j * 16 + ln) * 40 + quad * 8);
            s16x4 vb0, vb1;
            __builtin_memcpy(&vb0, vtb + ln * 136 + j * 16 + quad * 4, 8);
            __builtin_memcpy(&vb1, vtb + (16 + ln) * 136 + j * 16 + quad * 4, 8);
#pragma unroll
            for (int i = 0; i < 2; i++) {
                floatx4 s = __builtin_amdgcn_mfma_f32_16x16x32_bf16(kb, qa[i], zf, 0, 0, 0);
                bf16x4 p;
#pragma unroll
                for (int r = 0; r < 4; r++) {
                    float e = __builtin_amdgcn_exp2f(s[r]);
                    lsum[i] += e;
                    p[r] = (__bf16)e;
                }
                s16x4 pa;
                __builtin_memcpy(&pa, &p, 8);
                o[i][0] = __builtin_amdgcn_mfma_f32_16x16x16bf16_1k(pa, vb0, o[i][0], 0, 0, 0);
                o[i][1] = __builtin_amdgcn_mfma_f32_16x16x16bf16_1k(pa, vb1, o[i][1], 0, 0, 0);
            }
        }
    }
    // reduce row-sums across quads (col n = ln per lane)
#pragma unroll
    for (int i = 0; i < 2; i++) {
        lsum[i] += __shfl_xor(lsum[i], 16, 64);
        lsum[i] += __shfl_xor(lsum[i], 32, 64);
    }
    int b = bh >> 3, h = bh & 7;
#pragma unroll
    for (int i = 0; i < 2; i++)
#pragma unroll
        for (int r = 0; r < 4; r++) {
            float l_r = __shfl(lsum[i], quad * 4 + r, 64);
            float inv = 1.f / l_r;
            int n_g = n0 + i * 16 + quad * 4 + r;
#pragma unroll
            for (int dj = 0; dj < 2; dj++) {
                int f = h * HSZ + dj * 16 + ln;
                float val = o[i][dj][r] * inv + ppb[f];
                attn[((size_t)b * NN + n_g) * NF + f] = (__bf16)val;
            }
        }
}

// ---------------- K4: proj GEMM out[o,n] + residual ----------------
__launch_bounds__(256)
__global__ void k_proj(const __bf16* __restrict__ attn, const __bf16* __restrict__ wpb,
                       const float* __restrict__ x, const float* __restrict__ idsc,
                       float* __restrict__ out) {
    __shared__ __bf16 at[64 * 40];    // w_proj tile [64 o][32 f]
    __shared__ __bf16 bt[128 * 40];   // attn tile [128 n][32 f]
    int nt = blockIdx.x, ot = blockIdx.y, b = blockIdx.z;
    int tid = threadIdx.x, wave = tid >> 6, lane = tid & 63, ln = lane & 15, quad = lane >> 4;
    int wo = (wave & 1) * 32, wn = (wave >> 1) * 64;
    floatx4 acc[2][4];
#pragma unroll
    for (int i = 0; i < 2; i++)
#pragma unroll
        for (int j = 0; j < 4; j++) acc[i][j] = 0.f;
    const __bf16* asrc = wpb + (size_t)ot * 64 * NF;
    const __bf16* bsrc = attn + ((size_t)b * NN + nt * 128) * NF;
    for (int ko = 0; ko < 8; ko++) {
        __syncthreads();
        { int row = tid >> 2, cw = tid & 3;
          *(bf16x8*)(at + row * 40 + cw * 8) = *(const bf16x8*)(asrc + (size_t)row * NF + ko * 32 + cw * 8); }
#pragma unroll
        for (int t2 = 0; t2 < 2; t2++) {
            int ch = tid + t2 * 256;
            int row = ch >> 2, cw = ch & 3;
            *(bf16x8*)(bt + row * 40 + cw * 8) = *(const bf16x8*)(bsrc + (size_t)row * NF + ko * 32 + cw * 8);
        }
        __syncthreads();
        bf16x8 af[2], bfr[4];
#pragma unroll
        for (int oi = 0; oi < 2; oi++) af[oi]  = *(const bf16x8*)(at + (wo + oi * 16 + ln) * 40 + quad * 8);
#pragma unroll
        for (int nj = 0; nj < 4; nj++) bfr[nj] = *(const bf16x8*)(bt + (wn + nj * 16 + ln) * 40 + quad * 8);
#pragma unroll
        for (int oi = 0; oi < 2; oi++)
#pragma unroll
            for (int nj = 0; nj < 4; nj++)
                acc[oi][nj] = __builtin_amdgcn_mfma_f32_16x16x32_bf16(af[oi], bfr[nj], acc[oi][nj], 0, 0, 0);
    }
#pragma unroll
    for (int oi = 0; oi < 2; oi++)
#pragma unroll
        for (int nj = 0; nj < 4; nj++)
#pragma unroll
            for (int r = 0; r < 4; r++) {
                int o_g = ot * 64 + wo + oi * 16 + quad * 4 + r;
                int n_g = nt * 128 + wn + nj * 16 + ln;
                size_t idx = ((size_t)b * NF + o_g) * NN + n_g;
                out[idx] = x[idx] * idsc[o_g] + acc[oi][nj][r];
            }
}

// ---------------- launcher ----------------
extern "C" void kernel_launch(void* const* d_in, const int* in_sizes, int n_in,
                              void* d_out, int out_size, void* d_ws, size_t ws_size,
                              hipStream_t stream) {
    (void)in_sizes; (void)n_in; (void)out_size; (void)ws_size;
    const float* x    = (const float*)d_in[0];
    const float* mm   = (const float*)d_in[1];
    const float* mb   = (const float*)d_in[2];
    const float* wqkv = (const float*)d_in[3];
    const float* bqkv = (const float*)d_in[4];
    const float* wproj= (const float*)d_in[5];
    const float* peqh = (const float*)d_in[6];
    const float* peqw = (const float*)d_in[7];
    const float* pekh = (const float*)d_in[8];
    const float* pekw = (const float*)d_in[9];
    const float* pab  = (const float*)d_in[10];
    const float* pqb  = (const float*)d_in[11];
    const float* ppb  = (const float*)d_in[12];
    const float* idsc = (const float*)d_in[13];
    float* out = (float*)d_out;

    __bf16* ws = (__bf16*)d_ws;
    const size_t SEG = 2097152;            // elements per big buffer
    __bf16* y    = ws;
    __bf16* qs   = ws + SEG;
    __bf16* kst  = ws + SEG * 2;
    __bf16* vdm  = ws + SEG * 3;
    __bf16* attn = ws + SEG * 4;
    __bf16* wqb  = ws + SEG * 5;
    __bf16* wpb  = wqb + 196608;           // total ~21.5 MB

    hipLaunchKernelGGL(k_convert_w, dim3(1024), dim3(256), 0, stream, wqkv, wproj, wqb, wpb);
    hipLaunchKernelGGL(k_preact,    dim3(256), dim3(256), 0, stream, x, pab, pqb, y);
    hipLaunchKernelGGL(k_qkv,       dim3(32, 6, 2), dim3(256), 0, stream,
                       y, wqb, bqkv, peqh, peqw, pekh, pekw, mm, mb, qs, kst, vdm);
    hipLaunchKernelGGL(k_attn,      dim3(512), dim3(256), 0, stream, qs, kst, vdm, ppb, attn);
    hipLaunchKernelGGL(k_proj,      dim3(32, 4, 2), dim3(256), 0, stream, attn, wpb, x, idsc, out);
}

// Round 4
// 198.356 us; speedup vs baseline: 1.5991x; 1.0336x over previous
//
#include <hip/hip_runtime.h>
#include <hip/hip_bf16.h>
#include <cstdint>

// Problem constants
#define NB   2
#define NC   256
#define NN   4096   // H*W = 64*64
#define NH   8      // heads
#define HSZ  32     // head size
#define NF   256    // FEAT
#define N3F  768

typedef __bf16 bf16x8 __attribute__((ext_vector_type(8)));
typedef __bf16 bf16x4 __attribute__((ext_vector_type(4)));
typedef short  s16x4  __attribute__((ext_vector_type(4)));
typedef float  floatx4 __attribute__((ext_vector_type(4)));

// log2(e)/sqrt(32): folded into q so softmax runs in exp2 domain
#define QSCALE 0.25506601622184f

// ---------------- K0: prep = preact silu (blocks 0..255) + weight cvt (256..511) --
__global__ void k_prep(const float* __restrict__ x, const float* __restrict__ pab,
                       const float* __restrict__ pqb, __bf16* __restrict__ y,
                       const float* __restrict__ wqkv, const float* __restrict__ wproj,
                       __bf16* __restrict__ wqb, __bf16* __restrict__ wpb) {
    __shared__ __bf16 ct[32 * 264];           // [n][c], stride 264
    int bid = blockIdx.x, tid = threadIdx.x;
    if (bid >= 256) {                         // weight convert: 4 elems/thread
        int id = (bid - 256) * 1024 + tid * 4;
        const float* src = (id < 196608) ? (wqkv + id) : (wproj + (id - 196608));
        __bf16* dst = (id < 196608) ? (wqb + id) : (wpb + (id - 196608));
        float4 v = *(const float4*)src;
        bf16x4 o;
        o[0] = (__bf16)v.x; o[1] = (__bf16)v.y; o[2] = (__bf16)v.z; o[3] = (__bf16)v.w;
        *(bf16x4*)dst = o;
        return;
    }
    int b = bid >> 7, nt = bid & 127;
    int n0 = nt * 32;
    int cbase = tid >> 3, nc = tid & 7;       // n-chunk nc covers 4 n
#pragma unroll
    for (int q = 0; q < 8; q++) {
        int c = cbase + q * 32;
        const float4 xv = *(const float4*)(x + ((size_t)b * NC + c) * NN + n0 + nc * 4);
        float bias = pab[c], qb = pqb[c];
        float vs[4] = {xv.x, xv.y, xv.z, xv.w};
#pragma unroll
        for (int i = 0; i < 4; i++) {
            float s = vs[i] + bias;
            float r = s / (1.f + __expf(-s)) + qb;   // silu + pre_qkv_bias
            ct[(nc * 4 + i) * 264 + c] = (__bf16)r;
        }
    }
    __syncthreads();
#pragma unroll
    for (int q = 0; q < 4; q++) {
        int id = tid + q * 256;               // 1024 chunks
        int n = id >> 5, ck = (id & 31) * 8;
        bf16x8 v = *(const bf16x8*)(ct + n * 264 + ck);
        *(bf16x8*)(y + ((size_t)b * NN + n0 + n) * NC + ck) = v;
    }
}

// ---------------- K1: QKV GEMM out[n,o] = y_nc * w_qkv^T + epilogue ----------------
// Register-dbuf single-barrier K-loop. Epilogue via LDS so stores are 16B coalesced.
// Q -> qs[bh][n][d], K -> kst[bh][m][d], V -> vdm[bh][d][m] (direct transpose).
__launch_bounds__(256)
__global__ void k_qkv(const __bf16* __restrict__ y, const __bf16* __restrict__ wb,
                      const float* __restrict__ bqkv,
                      const float* __restrict__ peqh, const float* __restrict__ peqw,
                      const float* __restrict__ pekh, const float* __restrict__ pekw,
                      const float* __restrict__ mm, const float* __restrict__ mb,
                      __bf16* __restrict__ qs, __bf16* __restrict__ kst, __bf16* __restrict__ vdm) {
    __shared__ __bf16 smem[4 * 5120];    // at dbuf [2][5120] | bt dbuf [2][5120]; ct aliases
    __bf16* at0 = smem;
    __bf16* bt0 = smem + 2 * 5120;
    __bf16* ct  = smem;                  // 128*136 = 17408 <= 20480, reused after loop
    const int nt = blockIdx.x, ot = blockIdx.y, b = blockIdx.z;
    const int tid = threadIdx.x;
    const int wave = tid >> 6, lane = tid & 63, ln = lane & 15, quad = lane >> 4;
    const int wm = (wave & 1) * 64, wn = (wave >> 1) * 64;
    floatx4 acc[4][4];
#pragma unroll
    for (int i = 0; i < 4; i++)
#pragma unroll
        for (int j = 0; j < 4; j++) acc[i][j] = 0.f;
    const __bf16* ysrc = y + ((size_t)b * NN + nt * 128) * NC;
    const __bf16* wsrc = wb + (size_t)ot * 128 * NC;
    const int r0 = tid >> 2, c0 = (tid & 3) * 8;
    const int r1 = (tid + 256) >> 2, c1 = ((tid + 256) & 3) * 8;
    bf16x8 ya0, ya1, wa0, wa1;
    ya0 = *(const bf16x8*)(ysrc + (size_t)r0 * NC + c0);
    ya1 = *(const bf16x8*)(ysrc + (size_t)r1 * NC + c1);
    wa0 = *(const bf16x8*)(wsrc + (size_t)r0 * NC + c0);
    wa1 = *(const bf16x8*)(wsrc + (size_t)r1 * NC + c1);
    for (int ko = 0; ko < 8; ko++) {
        int buf = ko & 1;
        *(bf16x8*)(at0 + buf * 5120 + r0 * 40 + c0) = ya0;
        *(bf16x8*)(at0 + buf * 5120 + r1 * 40 + c1) = ya1;
        *(bf16x8*)(bt0 + buf * 5120 + r0 * 40 + c0) = wa0;
        *(bf16x8*)(bt0 + buf * 5120 + r1 * 40 + c1) = wa1;
        __syncthreads();
        if (ko < 7) {
            int kc = (ko + 1) * 32;
            ya0 = *(const bf16x8*)(ysrc + (size_t)r0 * NC + kc + c0);
            ya1 = *(const bf16x8*)(ysrc + (size_t)r1 * NC + kc + c1);
            wa0 = *(const bf16x8*)(wsrc + (size_t)r0 * NC + kc + c0);
            wa1 = *(const bf16x8*)(wsrc + (size_t)r1 * NC + kc + c1);
        }
        const __bf16* atb = at0 + buf * 5120;
        const __bf16* btb = bt0 + buf * 5120;
        bf16x8 af[4], bfr[4];
#pragma unroll
        for (int ii = 0; ii < 4; ii++) af[ii]  = *(const bf16x8*)(atb + (wm + ii * 16 + ln) * 40 + quad * 8);
#pragma unroll
        for (int jj = 0; jj < 4; jj++) bfr[jj] = *(const bf16x8*)(btb + (wn + jj * 16 + ln) * 40 + quad * 8);
#pragma unroll
        for (int ii = 0; ii < 4; ii++)
#pragma unroll
            for (int jj = 0; jj < 4; jj++)
                acc[ii][jj] = __builtin_amdgcn_mfma_f32_16x16x32_bf16(af[ii], bfr[jj], acc[ii][jj], 0, 0, 0);
    }
    __syncthreads();   // all frag reads done before ct (alias) is written
    // epilogue: C element (n_l = wm+ii*16+quad*4+r, o_l = wn+jj*16+ln)
    if (ot < 4) {
        // Q/K: ct[n][o]
#pragma unroll
        for (int ii = 0; ii < 4; ii++)
#pragma unroll
            for (int jj = 0; jj < 4; jj++) {
                int o_l = wn + jj * 16 + ln;
                int o_g = ot * 128 + o_l;
#pragma unroll
                for (int r = 0; r < 4; r++) {
                    int n_l = wm + ii * 16 + quad * 4 + r;
                    int n_g = nt * 128 + n_l;
                    int hp = n_g >> 6, wp = n_g & 63;
                    float val = acc[ii][jj][r] + bqkv[o_g];
                    if (ot < 2) {         // Q: PE + FiLM + fold softmax scale
                        val += peqh[o_g * 64 + hp] + peqw[o_g * 64 + wp];
                        val = val * mm[b * NF + o_g] + mb[b * NF + o_g];
                        val *= QSCALE;
                    } else {              // K: PE
                        int c = o_g - 256;
                        val += pekh[c * 64 + hp] + pekw[c * 64 + wp];
                    }
                    ct[n_l * 136 + o_l] = (__bf16)val;
                }
            }
        __syncthreads();
#pragma unroll
        for (int q = 0; q < 8; q++) {
            int id = tid + q * 256;       // 2048 chunks
            int n_l = id >> 4, oc = (id & 15) * 8;
            bf16x8 v = *(const bf16x8*)(ct + n_l * 136 + oc);
            int n_g = nt * 128 + n_l;
            int o_g = ot * 128 + oc;
            if (ot < 2) {
                int h = o_g >> 5, d = o_g & 31;
                *(bf16x8*)(qs + (((size_t)b * NH + h) * NN + n_g) * HSZ + d) = v;
            } else {
                int c = o_g - 256, h = c >> 5, d = c & 31;
                *(bf16x8*)(kst + (((size_t)b * NH + h) * NN + n_g) * HSZ + d) = v;
            }
        }
    } else {
        // V: ct[o][n] -> vdm[bh][d][m]
#pragma unroll
        for (int ii = 0; ii < 4; ii++)
#pragma unroll
            for (int jj = 0; jj < 4; jj++) {
                int o_l = wn + jj * 16 + ln;
                int o_g = ot * 128 + o_l;
#pragma unroll
                for (int r = 0; r < 4; r++) {
                    int n_l = wm + ii * 16 + quad * 4 + r;
                    float val = acc[ii][jj][r] + bqkv[o_g];
                    ct[o_l * 136 + n_l] = (__bf16)val;
                }
            }
        __syncthreads();
#pragma unroll
        for (int q = 0; q < 8; q++) {
            int id = tid + q * 256;
            int o_l = id >> 4, ncnk = (id & 15) * 8;
            bf16x8 v = *(const bf16x8*)(ct + o_l * 136 + ncnk);
            int c = ot * 128 + o_l - 512, h = c >> 5, d = c & 31;
            *(bf16x8*)(vdm + (((size_t)b * NH + h) * HSZ + d) * NN + nt * 128 + ncnk) = v;
        }
    }
}

// ---------------- K2: flash attention, split-K x2 (max-free -> partials add) ------
// 1024 blocks: [half][qt][bh-pair][xcd]. Each handles 2048 keys (16 tiles).
// Writes unnormalized partial O (bf16) + row-sum l (fp32).
__launch_bounds__(256)
__global__ void k_attn(const __bf16* __restrict__ qs, const __bf16* __restrict__ ksrc,
                       const __bf16* __restrict__ vdm,
                       __bf16* __restrict__ po, float* __restrict__ pl) {
    __shared__ __bf16 kt[2][128 * 40];    // K tile [m][d]
    __shared__ __bf16 vt[2][32 * 136];    // V tile [d][m]
    int bi = blockIdx.x;                  // 1024 blocks
    int xcd = bi & 7, r = bi >> 3;
    int bh = xcd * 2 + (r & 1);           // XCD owns 2 (b,h) pairs -> K/V in its L2
    int r2 = r >> 1;
    int qt = r2 & 31, half = r2 >> 5;
    int m_base = half * 2048;
    int tid = threadIdx.x, wave = tid >> 6, lane = tid & 63, ln = lane & 15, quad = lane >> 4;
    int n0 = qt * 128 + wave * 32;
    const __bf16* qbase = qs + (size_t)bh * NN * HSZ;
    const __bf16* kbase = ksrc + (size_t)bh * NN * HSZ;
    const __bf16* vbase = vdm + (size_t)bh * HSZ * NN;
    bf16x8 qa[2];
    qa[0] = *(const bf16x8*)(qbase + (size_t)(n0 + ln) * HSZ + quad * 8);
    qa[1] = *(const bf16x8*)(qbase + (size_t)(n0 + 16 + ln) * HSZ + quad * 8);
    floatx4 o[2][2];
    o[0][0] = 0.f; o[0][1] = 0.f; o[1][0] = 0.f; o[1][1] = 0.f;
    floatx4 lsum4[2];
    lsum4[0] = 0.f; lsum4[1] = 0.f;
    floatx4 zf = 0.f;
    const int k0r = tid >> 2, k0c = (tid & 3) * 8;
    const int k1r = (tid + 256) >> 2, k1c = ((tid + 256) & 3) * 8;
    const int v0d = tid >> 4, v0m = (tid & 15) * 8;
    const int v1d = (tid + 256) >> 4, v1m = ((tid + 256) & 15) * 8;
    bf16x8 krg0, krg1, vrg0, vrg1;
    krg0 = *(const bf16x8*)(kbase + (size_t)(m_base + k0r) * HSZ + k0c);
    krg1 = *(const bf16x8*)(kbase + (size_t)(m_base + k1r) * HSZ + k1c);
    vrg0 = *(const bf16x8*)(vbase + (size_t)v0d * NN + m_base + v0m);
    vrg1 = *(const bf16x8*)(vbase + (size_t)v1d * NN + m_base + v1m);

    for (int mt = 0; mt < 16; mt++) {
        int buf = mt & 1;
        *(bf16x8*)(&kt[buf][k0r * 40 + k0c]) = krg0;
        *(bf16x8*)(&kt[buf][k1r * 40 + k1c]) = krg1;
        *(bf16x8*)(&vt[buf][v0d * 136 + v0m]) = vrg0;
        *(bf16x8*)(&vt[buf][v1d * 136 + v1m]) = vrg1;
        __syncthreads();                  // single barrier per tile
        if (mt < 15) {                    // prefetch next tile into regs
            int m1 = m_base + (mt + 1) * 128;
            krg0 = *(const bf16x8*)(kbase + (size_t)(m1 + k0r) * HSZ + k0c);
            krg1 = *(const bf16x8*)(kbase + (size_t)(m1 + k1r) * HSZ + k1c);
            vrg0 = *(const bf16x8*)(vbase + (size_t)v0d * NN + m1 + v0m);
            vrg1 = *(const bf16x8*)(vbase + (size_t)v1d * NN + m1 + v1m);
        }
        const __bf16* ktb = &kt[buf][0];
        const __bf16* vtb = &vt[buf][0];
#pragma unroll
        for (int j = 0; j < 8; j++) {
            bf16x8 kb = *(const bf16x8*)(ktb + (j * 16 + ln) * 40 + quad * 8);
            s16x4 vb0, vb1;
            __builtin_memcpy(&vb0, vtb + ln * 136 + j * 16 + quad * 4, 8);
            __builtin_memcpy(&vb1, vtb + (16 + ln) * 136 + j * 16 + quad * 4, 8);
#pragma unroll
            for (int i = 0; i < 2; i++) {
                floatx4 s = __builtin_amdgcn_mfma_f32_16x16x32_bf16(kb, qa[i], zf, 0, 0, 0);
                bf16x4 p;
#pragma unroll
                for (int rr = 0; rr < 4; rr++) {
                    float e = __builtin_amdgcn_exp2f(s[rr]);
                    lsum4[i][rr] += e;               // 4 independent chains
                    p[rr] = (__bf16)e;
                }
                s16x4 pa;
                __builtin_memcpy(&pa, &p, 8);
                o[i][0] = __builtin_amdgcn_mfma_f32_16x16x16bf16_1k(pa, vb0, o[i][0], 0, 0, 0);
                o[i][1] = __builtin_amdgcn_mfma_f32_16x16x16bf16_1k(pa, vb1, o[i][1], 0, 0, 0);
            }
        }
    }
    // row-sums: components then cross-quad; every lane ends with l for col n = ln
    size_t pobase = (size_t)(half * 16 + bh) * NN * HSZ;
    size_t plbase = (size_t)(half * 16 + bh) * NN;
#pragma unroll
    for (int i = 0; i < 2; i++) {
        float ls = lsum4[i][0] + lsum4[i][1] + lsum4[i][2] + lsum4[i][3];
        ls += __shfl_xor(ls, 16, 64);
        ls += __shfl_xor(ls, 32, 64);
        if (quad == 0) pl[plbase + n0 + i * 16 + ln] = ls;
#pragma unroll
        for (int rr = 0; rr < 4; rr++) {
            int n_g = n0 + i * 16 + quad * 4 + rr;
#pragma unroll
            for (int dj = 0; dj < 2; dj++)
                po[pobase + (size_t)n_g * HSZ + dj * 16 + ln] = (__bf16)o[i][dj][rr];
        }
    }
}

// ---------------- K3: combine partials + proj GEMM out[o,n] + residual ------------
__launch_bounds__(256)
__global__ void k_proj(const __bf16* __restrict__ po, const float* __restrict__ pl,
                       const __bf16* __restrict__ wpb, const float* __restrict__ ppb,
                       const float* __restrict__ x, const float* __restrict__ idsc,
                       float* __restrict__ out) {
    __shared__ __bf16 at[64 * 264];    // w_proj tile [64 o][256 f]
    __shared__ __bf16 bt[2][128 * 40]; // combined attn tile [128 n][32 f]
    __shared__ float linv[8 * 128];    // 1/(l0+l1) per [h][n_l]
    __shared__ float ppbs[256];
    int nt = blockIdx.x, ot = blockIdx.y, b = blockIdx.z;
    int tid = threadIdx.x, wave = tid >> 6, lane = tid & 63, ln = lane & 15, quad = lane >> 4;
    int wo = (wave & 1) * 32, wn = (wave >> 1) * 64;
    // preload w_proj tile (all f)
#pragma unroll
    for (int q = 0; q < 8; q++) {
        int id = tid + q * 256;
        int row = id >> 5, fc = (id & 31) * 8;
        *(bf16x8*)(at + row * 264 + fc) = *(const bf16x8*)(wpb + (size_t)(ot * 64 + row) * NF + fc);
    }
    // preload 1/(l0+l1) for all 8 heads x 128 rows
#pragma unroll
    for (int q = 0; q < 4; q++) {
        int id = tid + q * 256;
        int h = id >> 7, n_l = id & 127;
        size_t base = (size_t)(b * NH + h) * NN + nt * 128 + n_l;
        linv[id] = 1.f / (pl[base] + pl[base + (size_t)16 * NN]);
    }
    ppbs[tid] = ppb[tid];
    __syncthreads();    // linv/ppbs/at ready before first commit uses them
    floatx4 acc[2][4];
#pragma unroll
    for (int i = 0; i < 2; i++)
#pragma unroll
        for (int j = 0; j < 4; j++) acc[i][j] = 0.f;
    // staging: thread -> row n_l = tid>>1, d-half = (tid&1)*16
    const int n_l = tid >> 1, dh = (tid & 1) * 16;
    const size_t prow = ((size_t)b * NH * NN + (size_t)nt * 128 + n_l) * HSZ + dh;  // h advances by NN*HSZ
    const size_t hstep = (size_t)NN * HSZ;
    const size_t half_off = (size_t)16 * NN * HSZ;
    bf16x8 p0a, p0b, p1a, p1b;
    p0a = *(const bf16x8*)(po + prow);
    p0b = *(const bf16x8*)(po + prow + 8);
    p1a = *(const bf16x8*)(po + prow + half_off);
    p1b = *(const bf16x8*)(po + prow + half_off + 8);
    for (int ko = 0; ko < 8; ko++) {
        int buf = ko & 1;
        // combine + normalize + ppb, commit to LDS
        float iv = linv[ko * 128 + n_l];
        bf16x8 c0, c1;
#pragma unroll
        for (int e = 0; e < 8; e++) {
            float v0 = ((float)p0a[e] + (float)p1a[e]) * iv + ppbs[ko * 32 + dh + e];
            float v1 = ((float)p0b[e] + (float)p1b[e]) * iv + ppbs[ko * 32 + dh + 8 + e];
            c0[e] = (__bf16)v0;
            c1[e] = (__bf16)v1;
        }
        *(bf16x8*)(&bt[buf][n_l * 40 + dh]) = c0;
        *(bf16x8*)(&bt[buf][n_l * 40 + dh + 8]) = c1;
        __syncthreads();
        if (ko < 7) {
            size_t pr = prow + (size_t)(ko + 1) * hstep;
            p0a = *(const bf16x8*)(po + pr);
            p0b = *(const bf16x8*)(po + pr + 8);
            p1a = *(const bf16x8*)(po + pr + half_off);
            p1b = *(const bf16x8*)(po + pr + half_off + 8);
        }
        bf16x8 af[2], bfr[4];
#pragma unroll
        for (int oi = 0; oi < 2; oi++) af[oi]  = *(const bf16x8*)(at + (wo + oi * 16 + ln) * 264 + ko * 32 + quad * 8);
#pragma unroll
        for (int nj = 0; nj < 4; nj++) bfr[nj] = *(const bf16x8*)(&bt[buf][(wn + nj * 16 + ln) * 40 + quad * 8]);
#pragma unroll
        for (int oi = 0; oi < 2; oi++)
#pragma unroll
            for (int nj = 0; nj < 4; nj++)
                acc[oi][nj] = __builtin_amdgcn_mfma_f32_16x16x32_bf16(af[oi], bfr[nj], acc[oi][nj], 0, 0, 0);
    }
#pragma unroll
    for (int oi = 0; oi < 2; oi++)
#pragma unroll
        for (int nj = 0; nj < 4; nj++)
#pragma unroll
            for (int r = 0; r < 4; r++) {
                int o_g = ot * 64 + wo + oi * 16 + quad * 4 + r;
                int n_g = nt * 128 + wn + nj * 16 + ln;
                size_t idx = ((size_t)b * NF + o_g) * NN + n_g;
                out[idx] = x[idx] * idsc[o_g] + acc[oi][nj][r];
            }
}

// ---------------- launcher ----------------
extern "C" void kernel_launch(void* const* d_in, const int* in_sizes, int n_in,
                              void* d_out, int out_size, void* d_ws, size_t ws_size,
                              hipStream_t stream) {
    (void)in_sizes; (void)n_in; (void)out_size; (void)ws_size;
    const float* x    = (const float*)d_in[0];
    const float* mm   = (const float*)d_in[1];
    const float* mb   = (const float*)d_in[2];
    const float* wqkv = (const float*)d_in[3];
    const float* bqkv = (const float*)d_in[4];
    const float* wproj= (const float*)d_in[5];
    const float* peqh = (const float*)d_in[6];
    const float* peqw = (const float*)d_in[7];
    const float* pekh = (const float*)d_in[8];
    const float* pekw = (const float*)d_in[9];
    const float* pab  = (const float*)d_in[10];
    const float* pqb  = (const float*)d_in[11];
    const float* ppb  = (const float*)d_in[12];
    const float* idsc = (const float*)d_in[13];
    float* out = (float*)d_out;

    __bf16* ws = (__bf16*)d_ws;
    const size_t SEG = 2097152;            // elements per big buffer
    __bf16* y    = ws;
    __bf16* qs   = ws + SEG;
    __bf16* kst  = ws + SEG * 2;
    __bf16* vdm  = ws + SEG * 3;
    __bf16* po   = ws + SEG * 4;           // 4M bf16 elems (2 halves x 16bh x 4096 x 32)
    float*  pl   = (float*)(ws + SEG * 6); // 131072 floats
    __bf16* wqb  = ws + SEG * 6 + 262144;
    __bf16* wpb  = wqb + 196608;           // total ~25.4 MB

    hipLaunchKernelGGL(k_prep, dim3(512), dim3(256), 0, stream,
                       x, pab, pqb, y, wqkv, wproj, wqb, wpb);
    hipLaunchKernelGGL(k_qkv,  dim3(32, 6, 2), dim3(256), 0, stream,
                       y, wqb, bqkv, peqh, peqw, pekh, pekw, mm, mb, qs, kst, vdm);
    hipLaunchKernelGGL(k_attn, dim3(1024), dim3(256), 0, stream, qs, kst, vdm, po, pl);
    hipLaunchKernelGGL(k_proj, dim3(32, 4, 2), dim3(256), 0, stream,
                       po, pl, wpb, ppb, x, idsc, out);
}

// Round 5
// 175.018 us; speedup vs baseline: 1.8124x; 1.1333x over previous
//
#include <hip/hip_runtime.h>
#include <hip/hip_bf16.h>
#include <cstdint>

// Problem constants
#define NB   2
#define NC   256
#define NN   4096   // H*W = 64*64
#define NH   8      // heads
#define HSZ  32     // head size
#define NF   256    // FEAT
#define N3F  768

typedef __bf16 bf16x8 __attribute__((ext_vector_type(8)));
typedef __bf16 bf16x4 __attribute__((ext_vector_type(4)));
typedef short  s16x4  __attribute__((ext_vector_type(4)));
typedef float  floatx4 __attribute__((ext_vector_type(4)));

// log2(e)/sqrt(32): folded into q so softmax runs in exp2 domain
#define QSCALE 0.25506601622184f

// ---------------- K0: prep = preact silu (blocks 0..255) + weight cvt (256..511) --
__global__ void k_prep(const float* __restrict__ x, const float* __restrict__ pab,
                       const float* __restrict__ pqb, __bf16* __restrict__ y,
                       const float* __restrict__ wqkv, const float* __restrict__ wproj,
                       __bf16* __restrict__ wqb, __bf16* __restrict__ wpb) {
    __shared__ __bf16 ct[32 * 264];           // [n][c], stride 264
    int bid = blockIdx.x, tid = threadIdx.x;
    if (bid >= 256) {                         // weight convert: 4 elems/thread
        int id = (bid - 256) * 1024 + tid * 4;
        const float* src = (id < 196608) ? (wqkv + id) : (wproj + (id - 196608));
        __bf16* dst = (id < 196608) ? (wqb + id) : (wpb + (id - 196608));
        float4 v = *(const float4*)src;
        bf16x4 o;
        o[0] = (__bf16)v.x; o[1] = (__bf16)v.y; o[2] = (__bf16)v.z; o[3] = (__bf16)v.w;
        *(bf16x4*)dst = o;
        return;
    }
    int b = bid >> 7, nt = bid & 127;
    int n0 = nt * 32;
    int cbase = tid >> 3, nc = tid & 7;       // n-chunk nc covers 4 n
#pragma unroll
    for (int q = 0; q < 8; q++) {
        int c = cbase + q * 32;
        const float4 xv = *(const float4*)(x + ((size_t)b * NC + c) * NN + n0 + nc * 4);
        float bias = pab[c], qb = pqb[c];
        float vs[4] = {xv.x, xv.y, xv.z, xv.w};
#pragma unroll
        for (int i = 0; i < 4; i++) {
            float s = vs[i] + bias;
            float r = s / (1.f + __expf(-s)) + qb;   // silu + pre_qkv_bias
            ct[(nc * 4 + i) * 264 + c] = (__bf16)r;
        }
    }
    __syncthreads();
#pragma unroll
    for (int q = 0; q < 4; q++) {
        int id = tid + q * 256;               // 1024 chunks
        int n = id >> 5, ck = (id & 31) * 8;
        bf16x8 v = *(const bf16x8*)(ct + n * 264 + ck);
        *(bf16x8*)(y + ((size_t)b * NN + n0 + n) * NC + ck) = v;
    }
}

// ---------------- K1: QKV GEMM, 64x64 tiles. Q->qs[bh][n][d]; K,V->fragment-major --
// kf: per (bh, mt=m/16): 512-elem block; lane l elem (l*8+e) = K[m0 + (l&15)][ (l>>4)*8 + e ]
// vf: per (bh, mt):      512-elem block; elem (l*8 + dj*4 + e) = V[m0 + (l>>4)*4 + e][ dj*16 + (l&15) ]
__launch_bounds__(256)
__global__ void k_qkv(const __bf16* __restrict__ y, const __bf16* __restrict__ wb,
                      const float* __restrict__ bqkv,
                      const float* __restrict__ peqh, const float* __restrict__ peqw,
                      const float* __restrict__ pekh, const float* __restrict__ pekw,
                      const float* __restrict__ mm, const float* __restrict__ mb,
                      __bf16* __restrict__ qs, __bf16* __restrict__ kf, __bf16* __restrict__ vf) {
    __shared__ __bf16 smem[4][64 * 40];  // [a0 a1 b0 b1]; ct (64*72=4608) aliases smem[0..1]
    __bf16* ct = &smem[0][0];
    const int nt = blockIdx.x, ot = blockIdx.y, b = blockIdx.z;   // grid (64, 12, 2)
    const int tid = threadIdx.x;
    const int wave = tid >> 6, lane = tid & 63, ln = lane & 15, quad = lane >> 4;
    const int wm = (wave & 1) * 32, wn = (wave >> 1) * 32;
    floatx4 acc[2][2];
#pragma unroll
    for (int i = 0; i < 2; i++)
#pragma unroll
        for (int j = 0; j < 2; j++) acc[i][j] = 0.f;
    const __bf16* ysrc = y + ((size_t)b * NN + nt * 64) * NC;
    const __bf16* wsrc = wb + (size_t)ot * 64 * NC;
    const int r0 = tid >> 2, c0 = (tid & 3) * 8;
    bf16x8 ya = *(const bf16x8*)(ysrc + (size_t)r0 * NC + c0);
    bf16x8 wa = *(const bf16x8*)(wsrc + (size_t)r0 * NC + c0);
    for (int ko = 0; ko < 8; ko++) {
        int buf = ko & 1;
        *(bf16x8*)(&smem[buf][r0 * 40 + c0]) = ya;
        *(bf16x8*)(&smem[2 + buf][r0 * 40 + c0]) = wa;
        __syncthreads();
        if (ko < 7) {
            int kc = (ko + 1) * 32;
            ya = *(const bf16x8*)(ysrc + (size_t)r0 * NC + kc + c0);
            wa = *(const bf16x8*)(wsrc + (size_t)r0 * NC + kc + c0);
        }
        bf16x8 af[2], bfr[2];
#pragma unroll
        for (int ii = 0; ii < 2; ii++) af[ii]  = *(const bf16x8*)(&smem[buf][(wm + ii * 16 + ln) * 40 + quad * 8]);
#pragma unroll
        for (int jj = 0; jj < 2; jj++) bfr[jj] = *(const bf16x8*)(&smem[2 + buf][(wn + jj * 16 + ln) * 40 + quad * 8]);
#pragma unroll
        for (int ii = 0; ii < 2; ii++)
#pragma unroll
            for (int jj = 0; jj < 2; jj++)
                acc[ii][jj] = __builtin_amdgcn_mfma_f32_16x16x32_bf16(af[ii], bfr[jj], acc[ii][jj], 0, 0, 0);
    }
    __syncthreads();   // frag reads done before ct alias is written
    if (ot < 8) {
        // Q/K: ct[n_l][o_l]
#pragma unroll
        for (int ii = 0; ii < 2; ii++)
#pragma unroll
            for (int jj = 0; jj < 2; jj++) {
                int o_l = wn + jj * 16 + ln;
                int o_g = ot * 64 + o_l;
                float bq = bqkv[o_g];
#pragma unroll
                for (int r = 0; r < 4; r++) {
                    int n_l = wm + ii * 16 + quad * 4 + r;
                    float val = acc[ii][jj][r] + bq;
                    if (ot < 4) {         // Q: PE + FiLM + softmax scale
                        val += peqh[o_g * 64 + nt] + peqw[o_g * 64 + n_l];
                        val = val * mm[b * NF + o_g] + mb[b * NF + o_g];
                        val *= QSCALE;
                    } else {              // K: PE
                        int c = o_g - 256;
                        val += pekh[c * 64 + nt] + pekw[c * 64 + n_l];
                    }
                    ct[n_l * 72 + o_l] = (__bf16)val;
                }
            }
        __syncthreads();
#pragma unroll
        for (int q = 0; q < 2; q++) {
            int id = tid + q * 256;       // 512 chunks
            int n_l = id >> 3, oc = (id & 7) * 8;
            bf16x8 v = *(const bf16x8*)(ct + n_l * 72 + oc);
            int n_g = nt * 64 + n_l;
            int o_g = ot * 64 + oc;
            if (ot < 4) {
                int h = o_g >> 5, d = o_g & 31;
                *(bf16x8*)(qs + (((size_t)b * NH + h) * NN + n_g) * HSZ + d) = v;
            } else {
                int c = o_g - 256, h = c >> 5, d0 = c & 31;
                size_t blk = ((size_t)(b * NH + h) * 256 + (n_g >> 4)) * 512;
                *(bf16x8*)(kf + blk + (d0 >> 3) * 128 + (n_g & 15) * 8) = v;
            }
        }
    } else {
        // V: ct[o_l][n_l] -> vf fragment-major
#pragma unroll
        for (int ii = 0; ii < 2; ii++)
#pragma unroll
            for (int jj = 0; jj < 2; jj++) {
                int o_l = wn + jj * 16 + ln;
                float bq = bqkv[ot * 64 + o_l];
#pragma unroll
                for (int r = 0; r < 4; r++) {
                    int n_l = wm + ii * 16 + quad * 4 + r;
                    ct[o_l * 72 + n_l] = (__bf16)(acc[ii][jj][r] + bq);
                }
            }
        __syncthreads();
#pragma unroll
        for (int q = 0; q < 4; q++) {
            int id = tid + q * 256;       // 1024 slots of 4 elems
            int o_l = id >> 4, ng4 = (id & 15) * 4;
            bf16x4 v = *(const bf16x4*)(ct + o_l * 72 + ng4);
            int c = (ot - 8) * 64 + o_l, h = c >> 5, d = c & 31;
            int dj = d >> 4, lnv = d & 15;
            int m_g = nt * 64 + ng4;
            size_t blk = ((size_t)(b * NH + h) * 256 + (m_g >> 4)) * 512;
            *(bf16x4*)(vf + blk + (((m_g >> 2) & 3) * 16 + lnv) * 8 + dj * 4) = v;
        }
    }
}

// ---------------- K2: flash attention, split-K x2, fragment-major LDS, ones-MFMA ---
__launch_bounds__(256)
__global__ void k_attn(const __bf16* __restrict__ qs, const __bf16* __restrict__ kf,
                       const __bf16* __restrict__ vf,
                       __bf16* __restrict__ po, float* __restrict__ pl) {
    __shared__ __bf16 sbuf[2 * 8192];     // per buf: [kf 4096 | vf 4096] elems
    int bi = blockIdx.x;                  // 1024 blocks
    int xcd = bi & 7, r = bi >> 3;
    int bh = xcd * 2 + (r & 1);           // XCD owns 2 (b,h) pairs
    int r2 = r >> 1;
    int qt = r2 & 31, half = r2 >> 5;
    int tid = threadIdx.x, wave = tid >> 6, lane = tid & 63, ln = lane & 15, quad = lane >> 4;
    int n0 = qt * 128 + wave * 32;
    const __bf16* qbase = qs + (size_t)bh * NN * HSZ;
    const __bf16* kfb = kf + ((size_t)bh * 256 + half * 128) * 512;
    const __bf16* vfb = vf + ((size_t)bh * 256 + half * 128) * 512;
    bf16x8 qa[2];
    qa[0] = *(const bf16x8*)(qbase + (size_t)(n0 + ln) * HSZ + quad * 8);
    qa[1] = *(const bf16x8*)(qbase + (size_t)(n0 + 16 + ln) * HSZ + quad * 8);
    floatx4 o[2][2], o2[2];
    o[0][0] = 0.f; o[0][1] = 0.f; o[1][0] = 0.f; o[1][1] = 0.f;
    o2[0] = 0.f; o2[1] = 0.f;
    floatx4 zf = 0.f;
    s16x4 ones;
    ones[0] = (short)0x3F80; ones[1] = (short)0x3F80;
    ones[2] = (short)0x3F80; ones[3] = (short)0x3F80;   // bf16 1.0
    const int toff = tid * 8;             // staging: elems
    const int lo = lane * 8;
    bf16x8 kr0, kr1, vr0, vr1;
    kr0 = *(const bf16x8*)(kfb + toff);
    kr1 = *(const bf16x8*)(kfb + toff + 2048);
    vr0 = *(const bf16x8*)(vfb + toff);
    vr1 = *(const bf16x8*)(vfb + toff + 2048);
    for (int mt = 0; mt < 16; mt++) {
        int bo = (mt & 1) << 13;
        *(bf16x8*)(sbuf + bo + toff) = kr0;
        *(bf16x8*)(sbuf + bo + toff + 2048) = kr1;
        *(bf16x8*)(sbuf + bo + 4096 + toff) = vr0;
        *(bf16x8*)(sbuf + bo + 4096 + toff + 2048) = vr1;
        __syncthreads();                  // single barrier per tile
        if (mt < 15) {
            const __bf16* kn = kfb + (mt + 1) * 4096;
            const __bf16* vn = vfb + (mt + 1) * 4096;
            kr0 = *(const bf16x8*)(kn + toff);
            kr1 = *(const bf16x8*)(kn + toff + 2048);
            vr0 = *(const bf16x8*)(vn + toff);
            vr1 = *(const bf16x8*)(vn + toff + 2048);
        }
        const __bf16* kl = sbuf + bo;
        const __bf16* vl = sbuf + bo + 4096;
#pragma unroll
        for (int j = 0; j < 8; j++) {
            bf16x8 kfr = *(const bf16x8*)(kl + j * 512 + lo);
            bf16x8 vfr = *(const bf16x8*)(vl + j * 512 + lo);
            s16x4 vb0, vb1;
            __builtin_memcpy(&vb0, &vfr, 8);
            __builtin_memcpy(&vb1, (const char*)&vfr + 8, 8);
#pragma unroll
            for (int i = 0; i < 2; i++) {
                floatx4 s = __builtin_amdgcn_mfma_f32_16x16x32_bf16(kfr, qa[i], zf, 0, 0, 0);
                bf16x4 p;
#pragma unroll
                for (int rr = 0; rr < 4; rr++)
                    p[rr] = (__bf16)__builtin_amdgcn_exp2f(s[rr]);
                s16x4 pa;
                __builtin_memcpy(&pa, &p, 8);
                o[i][0] = __builtin_amdgcn_mfma_f32_16x16x16bf16_1k(pa, vb0, o[i][0], 0, 0, 0);
                o[i][1] = __builtin_amdgcn_mfma_f32_16x16x16bf16_1k(pa, vb1, o[i][1], 0, 0, 0);
                o2[i]   = __builtin_amdgcn_mfma_f32_16x16x16bf16_1k(pa, ones, o2[i], 0, 0, 0);
            }
        }
    }
    // epilogue: o2[i][r] = row-sum l for n = n0+i*16+quad*4+r (all lanes of quad agree)
    size_t plbase = (size_t)(half * 16 + bh) * NN;
    if (ln == 0)
#pragma unroll
        for (int i = 0; i < 2; i++)
#pragma unroll
            for (int rr = 0; rr < 4; rr++)
                pl[plbase + n0 + i * 16 + quad * 4 + rr] = o2[i][rr];
    // po via LDS (waves write their own 32-row stripe of [128][32]; mt=15 used hi buf)
    __bf16* ct = sbuf;                    // 128*32 = 4096 elems
#pragma unroll
    for (int i = 0; i < 2; i++)
#pragma unroll
        for (int dj = 0; dj < 2; dj++)
#pragma unroll
            for (int rr = 0; rr < 4; rr++)
                ct[(wave * 32 + i * 16 + quad * 4 + rr) * 32 + dj * 16 + ln] = (__bf16)o[i][dj][rr];
    __syncthreads();
    size_t pobase = ((size_t)(half * 16 + bh) * NN + (size_t)qt * 128) * HSZ;
#pragma unroll
    for (int q = 0; q < 2; q++) {
        int id = tid + q * 256;           // 512 chunks
        int n_l = id >> 2, dc = (id & 3) * 8;
        *(bf16x8*)(po + pobase + n_l * HSZ + dc) = *(const bf16x8*)(ct + n_l * 32 + dc);
    }
}

// ---------------- K3: combine partials + proj GEMM out[o,n] + residual (64x64) ----
__launch_bounds__(256)
__global__ void k_proj(const __bf16* __restrict__ po, const float* __restrict__ pl,
                       const __bf16* __restrict__ wpb, const float* __restrict__ ppb,
                       const float* __restrict__ x, const float* __restrict__ idsc,
                       float* __restrict__ out) {
    __shared__ __bf16 at[64 * 264];    // w_proj tile [64 o][256 f]
    __shared__ __bf16 bt[2][64 * 40];  // combined attn tile [64 n][32 f]
    __shared__ float linv[8 * 64];
    __shared__ float ppbs[256];
    int nt = blockIdx.x, ot = blockIdx.y, b = blockIdx.z;   // grid (64, 4, 2)
    int tid = threadIdx.x, wave = tid >> 6, lane = tid & 63, ln = lane & 15, quad = lane >> 4;
    int wo = (wave & 1) * 32, wn = (wave >> 1) * 32;
#pragma unroll
    for (int q = 0; q < 8; q++) {
        int id = tid + q * 256;
        int row = id >> 5, fc = (id & 31) * 8;
        *(bf16x8*)(at + row * 264 + fc) = *(const bf16x8*)(wpb + (size_t)(ot * 64 + row) * NF + fc);
    }
#pragma unroll
    for (int q = 0; q < 2; q++) {
        int id = tid + q * 256;           // 512 = 8h x 64n
        int h = id >> 6, n_l = id & 63;
        size_t base = (size_t)(b * NH + h) * NN + nt * 64 + n_l;
        linv[id] = 1.f / (pl[base] + pl[base + (size_t)16 * NN]);
    }
    ppbs[tid] = ppb[tid];
    __syncthreads();
    floatx4 acc[2][2];
#pragma unroll
    for (int i = 0; i < 2; i++)
#pragma unroll
        for (int j = 0; j < 2; j++) acc[i][j] = 0.f;
    const int n_l = tid >> 2, dh8 = (tid & 3) * 8;
    const size_t hstep = (size_t)NN * HSZ;
    const size_t half_off = (size_t)16 * NN * HSZ;
    size_t prow = ((size_t)b * NH * NN + (size_t)nt * 64 + n_l) * HSZ + dh8;
    bf16x8 p0 = *(const bf16x8*)(po + prow);
    bf16x8 p1 = *(const bf16x8*)(po + prow + half_off);
    for (int ko = 0; ko < 8; ko++) {
        int buf = ko & 1;
        float iv = linv[ko * 64 + n_l];
        bf16x8 c;
#pragma unroll
        for (int e = 0; e < 8; e++)
            c[e] = (__bf16)(((float)p0[e] + (float)p1[e]) * iv + ppbs[ko * 32 + dh8 + e]);
        *(bf16x8*)(&bt[buf][n_l * 40 + dh8]) = c;
        __syncthreads();
        if (ko < 7) {
            size_t pr = prow + (size_t)(ko + 1) * hstep;
            p0 = *(const bf16x8*)(po + pr);
            p1 = *(const bf16x8*)(po + pr + half_off);
        }
        bf16x8 af[2], bfr[2];
#pragma unroll
        for (int oi = 0; oi < 2; oi++) af[oi]  = *(const bf16x8*)(at + (wo + oi * 16 + ln) * 264 + ko * 32 + quad * 8);
#pragma unroll
        for (int nj = 0; nj < 2; nj++) bfr[nj] = *(const bf16x8*)(&bt[buf][(wn + nj * 16 + ln) * 40 + quad * 8]);
#pragma unroll
        for (int oi = 0; oi < 2; oi++)
#pragma unroll
            for (int nj = 0; nj < 2; nj++)
                acc[oi][nj] = __builtin_amdgcn_mfma_f32_16x16x32_bf16(af[oi], bfr[nj], acc[oi][nj], 0, 0, 0);
    }
#pragma unroll
    for (int oi = 0; oi < 2; oi++)
#pragma unroll
        for (int nj = 0; nj < 2; nj++)
#pragma unroll
            for (int r = 0; r < 4; r++) {
                int o_g = ot * 64 + wo + oi * 16 + quad * 4 + r;
                int n_g = nt * 64 + wn + nj * 16 + ln;
                size_t idx = ((size_t)b * NF + o_g) * NN + n_g;
                out[idx] = x[idx] * idsc[o_g] + acc[oi][nj][r];
            }
}

// ---------------- launcher ----------------
extern "C" void kernel_launch(void* const* d_in, const int* in_sizes, int n_in,
                              void* d_out, int out_size, void* d_ws, size_t ws_size,
                              hipStream_t stream) {
    (void)in_sizes; (void)n_in; (void)out_size; (void)ws_size;
    const float* x    = (const float*)d_in[0];
    const float* mm   = (const float*)d_in[1];
    const float* mb   = (const float*)d_in[2];
    const float* wqkv = (const float*)d_in[3];
    const float* bqkv = (const float*)d_in[4];
    const float* wproj= (const float*)d_in[5];
    const float* peqh = (const float*)d_in[6];
    const float* peqw = (const float*)d_in[7];
    const float* pekh = (const float*)d_in[8];
    const float* pekw = (const float*)d_in[9];
    const float* pab  = (const float*)d_in[10];
    const float* pqb  = (const float*)d_in[11];
    const float* ppb  = (const float*)d_in[12];
    const float* idsc = (const float*)d_in[13];
    float* out = (float*)d_out;

    __bf16* ws = (__bf16*)d_ws;
    const size_t SEG = 2097152;            // elements per big buffer
    __bf16* y    = ws;
    __bf16* qs   = ws + SEG;
    __bf16* kf   = ws + SEG * 2;
    __bf16* vf   = ws + SEG * 3;
    __bf16* po   = ws + SEG * 4;           // 2 halves x 16bh x 4096 x 32
    float*  pl   = (float*)(ws + SEG * 6); // 131072 floats
    __bf16* wqb  = ws + SEG * 6 + 262144;
    __bf16* wpb  = wqb + 196608;

    hipLaunchKernelGGL(k_prep, dim3(512), dim3(256), 0, stream,
                       x, pab, pqb, y, wqkv, wproj, wqb, wpb);
    hipLaunchKernelGGL(k_qkv,  dim3(64, 12, 2), dim3(256), 0, stream,
                       y, wqb, bqkv, peqh, peqw, pekh, pekw, mm, mb, qs, kf, vf);
    hipLaunchKernelGGL(k_attn, dim3(1024), dim3(256), 0, stream, qs, kf, vf, po, pl);
    hipLaunchKernelGGL(k_proj, dim3(64, 4, 2), dim3(256), 0, stream,
                       po, pl, wpb, ppb, x, idsc, out);
}